// Round 3
// baseline (27005.353 us; speedup 1.0000x reference)
//
#include <hip/hip_runtime.h>
#include <hip/hip_cooperative_groups.h>

#define LSEQ 128
#define BATCH 1024
#define DDIM 512
#define G3 1536
#define HS ((size_t)BATCH * DDIM)   // one state slot
#define INV2048 4.8828125e-4f

typedef _Float16 h8 __attribute__((ext_vector_type(8)));
typedef float floatx4 __attribute__((ext_vector_type(4)));

#define MFMA16(acc, A, B) acc = __builtin_amdgcn_mfma_f32_16x16x32_f16(A, B, acc, 0, 0, 0)

// split x = hi + lo*2^-11 ; lo stored pre-scaled by 2^11 so it stays in fp16 normal range
__device__ __forceinline__ void fsplitS(float x, _Float16* hi, _Float16* lo) {
    _Float16 h = (_Float16)x;
    *hi = h;
    *lo = (_Float16)((x - (float)h) * 2048.0f);
}

// ---------------- prep: weight splits/transposes, state zero, y[0] ----------------
__global__ void prep_kernel(const float* __restrict__ Wih, const float* __restrict__ Whh,
                            const float* __restrict__ W1, const float* __restrict__ W2,
                            const float* __restrict__ WLy, const float* __restrict__ bLy,
                            _Float16* __restrict__ Wih_hi, _Float16* __restrict__ Wih_lo,
                            _Float16* __restrict__ Whh_lo,
                            _Float16* __restrict__ W1T_hi, _Float16* __restrict__ W1T_lo,
                            _Float16* __restrict__ W2T_hi, _Float16* __restrict__ W2T_lo,
                            _Float16* __restrict__ WLyT_hi, _Float16* __restrict__ WLyT_lo,
                            float* __restrict__ hn_f32, _Float16* __restrict__ hn_hi,
                            _Float16* __restrict__ hn_lo, float* __restrict__ out)
{
    int tid = blockIdx.x * 256 + threadIdx.x;   // 65536 threads
    for (int i = tid; i < G3 * DDIM; i += 65536) fsplitS(Wih[i], &Wih_hi[i], &Wih_lo[i]);
    for (int i = tid; i < G3 * DDIM; i += 65536) { _Float16 d; fsplitS(Whh[i], &d, &Whh_lo[i]); }
    for (int i = tid; i < 128 * 256; i += 65536) { int n = i >> 8, k = i & 255; fsplitS(W1[k * 128 + n], &W1T_hi[i], &W1T_lo[i]); }
    for (int i = tid; i < 256 * 128; i += 65536) { int n = i >> 7, k = i & 127; fsplitS(W2[k * 256 + n], &W2T_hi[i], &W2T_lo[i]); }
    for (int i = tid; i < 16 * 512;  i += 65536) { int n = i >> 9, k = i & 511; fsplitS(WLy[k * 16 + n], &WLyT_hi[i], &WLyT_lo[i]); }
    // zero state slot 0 only (slot 1 is fully written at step 0 before first read)
    for (int i = tid; i < BATCH * DDIM; i += 65536) { hn_f32[i] = 0.f; hn_hi[i] = (_Float16)0.f; hn_lo[i] = (_Float16)0.f; }
    for (int i = tid; i < BATCH * 16; i += 65536) out[i] = bLy[i & 15];   // y[0] = bLy (h0 = 0)
}

// ---------------- shared embedding routine: 8 rows x 512 cols of xcat[t] ----------------
__device__ __forceinline__ void embed_rows(const float* __restrict__ ext, const float* __restrict__ obs,
                                           const float* __restrict__ Wu, const float* __restrict__ bu,
                                           const float* __restrict__ Wx, const float* __restrict__ bx,
                                           int t, int r0, int tid, float* stg,
                                           _Float16* __restrict__ oh, _Float16* __restrict__ ol)
{
    for (int i = tid; i < 256; i += 512) stg[i] = ext[((size_t)t * BATCH + r0 + (i >> 5)) * 33 + (i & 31)];
    for (int i = tid; i < 128; i += 512) stg[256 + i] = obs[((size_t)t * BATCH + r0 + (i >> 4)) * 16 + (i & 15)];
    __syncthreads();
    int c = tid;   // 512 threads <-> 512 cols
    if (c < 256) {
        float wv[32];
        #pragma unroll
        for (int k = 0; k < 32; ++k) wv[k] = Wu[k * 256 + c];
        float b = bu[c];
        for (int r = 0; r < 8; ++r) {
            float acc = b;
            #pragma unroll
            for (int k = 0; k < 32; ++k) acc += stg[r * 32 + k] * wv[k];
            size_t p = (size_t)(r0 + r) * DDIM + c;
            fsplitS(tanhf(acc), &oh[p], &ol[p]);
        }
    } else {
        int cc = c - 256;
        float wv[16];
        #pragma unroll
        for (int k = 0; k < 16; ++k) wv[k] = Wx[k * 256 + cc];
        float b = bx[cc];
        for (int r = 0; r < 8; ++r) {
            float acc = b;
            #pragma unroll
            for (int k = 0; k < 16; ++k) acc += stg[256 + r * 16 + k] * wv[k];
            size_t p = (size_t)(r0 + r) * DDIM + c;
            fsplitS(tanhf(acc), &oh[p], &ol[p]);
        }
    }
}

// ---------------- embed0: xcat for t=0 into slot 0 (before cooperative kernel) ----------------
__global__ void embed0_kernel(const float* __restrict__ ext, const float* __restrict__ obs,
                              const float* __restrict__ Wu, const float* __restrict__ bu,
                              const float* __restrict__ Wx, const float* __restrict__ bx,
                              _Float16* __restrict__ xcb_hi, _Float16* __restrict__ xcb_lo)
{
    __shared__ float stg[384];
    embed_rows(ext, obs, Wu, bu, Wx, bx, 0, blockIdx.x * 8, threadIdx.x, stg, xcb_hi, xcb_lo);
}

// ---------------- main persistent cooperative scan kernel ----------------
struct MainArgs {
    const float* ext;
    const float* obs;
    const float* Wu; const float* bu;
    const float* Wx; const float* bx;
    const float* Whh;       // fp32, hi-split on LDS fill
    const float* b_ih;
    const float* b_hh;
    const float* b1;
    const float* b2;
    const float* bLy;
    const _Float16* Wih_hi; const _Float16* Wih_lo;
    const _Float16* Whh_lo;
    const _Float16* W1T_hi; const _Float16* W1T_lo;
    const _Float16* W2T_hi; const _Float16* W2T_lo;
    const _Float16* WLyT_hi; const _Float16* WLyT_lo;
    _Float16* xcb_hi; _Float16* xcb_lo;     // 2 slots, rotating
    float* hn_f32;                          // 2 slots
    _Float16* hn_hi; _Float16* hn_lo;       // 2 slots
    float* bufB;
    float* out;
};

#define WST 520    // LDS W row stride (halves): 16B-aligned rows, mild bank alias only
#define CP  33     // gate scratch row stride (floats)

__global__ void __launch_bounds__(512, 1) main_kernel(MainArgs a)
{
    __shared__ _Float16 sWhi[96 * WST];          // 99,840 B : W_hh-hi slice, resident
    __shared__ float sC[4 * 64 * CP];            // 33,792 B : r,z,ni,nh planes (B overlays)
    __shared__ _Float16 sZ1[2 * 16 * 136];       //  8,704 B : z1 hi|lo (embed blocks reuse as stage)

    namespace cg = cooperative_groups;
    cg::grid_group grid = cg::this_grid();

    const int blk  = blockIdx.x;      // 0..255
    const int gb   = blk >> 4;        // batch block (64 rows)
    const int gn   = blk & 15;        // hn-col block (32 cols -> 96 gate rows)
    const int tid  = threadIdx.x;
    const int lane = tid & 63;
    const int w    = tid >> 6;        // 0..7
    const int mw   = w >> 1;          // m-tile (16 rows each, 4 tiles = 64 rows)
    const int nw   = w & 1;           // n-half (16 of the 32 hn cols)
    const int l15  = lane & 15;
    const int l4   = lane >> 4;
    const int row0 = gb * 64;
    const int arow = row0 + mw * 16 + l15;

    // W rows this wave's B-fragments address
    const int    lwR = (nw * 16 + l15) * WST;
    const int    lwZ = (32 + nw * 16 + l15) * WST;
    const int    lwN = (64 + nw * 16 + l15) * WST;
    const size_t ghR = (size_t)(gn * 32 + nw * 16 + l15) * DDIM;
    const size_t ghZ = (size_t)(512 + gn * 32 + nw * 16 + l15) * DDIM;
    const size_t ghN = (size_t)(1024 + gn * 32 + nw * 16 + l15) * DDIM;

    // Fill LDS with hi-split of this block's W_hh slice (96 rows x 512)
    for (int i = tid; i < 96 * 512; i += 512) {
        int p = i >> 9, k = i & 511;
        int g = (p >> 5) * 512 + gn * 32 + (p & 31);
        sWhi[p * WST + k] = (_Float16)a.Whh[(size_t)g * DDIM + k];
    }
    __syncthreads();

    for (int t = 0; t < LSEQ; ++t) {
        const int cur = t & 1, nxt = cur ^ 1;

        // ---------------- Phase A: gi+gh (split-fp16, scaled-lo correction) ----------------
        floatx4 aR  = {0.f,0.f,0.f,0.f}, aZ  = {0.f,0.f,0.f,0.f};
        floatx4 aNI = {0.f,0.f,0.f,0.f}, aNH = {0.f,0.f,0.f,0.f};
        floatx4 cR  = {0.f,0.f,0.f,0.f}, cZ  = {0.f,0.f,0.f,0.f};
        floatx4 cNI = {0.f,0.f,0.f,0.f}, cNH = {0.f,0.f,0.f,0.f};
        const _Float16* xh = a.xcb_hi + (size_t)cur * HS + (size_t)arow * DDIM;
        const _Float16* xl = a.xcb_lo + (size_t)cur * HS + (size_t)arow * DDIM;
        const _Float16* hh = a.hn_hi  + (size_t)cur * HS + (size_t)arow * DDIM;
        const _Float16* hl = a.hn_lo  + (size_t)cur * HS + (size_t)arow * DDIM;

        for (int kk = 0; kk < 16; ++kk) {
            const int k = kk * 32 + l4 * 8;
            h8 Axh = *(const h8*)(xh + k);
            h8 Axl = *(const h8*)(xl + k);
            h8 Ahh = *(const h8*)(hh + k);
            h8 Ahl = *(const h8*)(hl + k);
            h8 BRh = *(const h8*)(a.Wih_hi + ghR + k);
            h8 BRl = *(const h8*)(a.Wih_lo + ghR + k);
            h8 BZh = *(const h8*)(a.Wih_hi + ghZ + k);
            h8 BZl = *(const h8*)(a.Wih_lo + ghZ + k);
            h8 BNh = *(const h8*)(a.Wih_hi + ghN + k);
            h8 BNl = *(const h8*)(a.Wih_lo + ghN + k);
            h8 WRh = *(const h8*)(sWhi + lwR + k);
            h8 WZh = *(const h8*)(sWhi + lwZ + k);
            h8 WNh = *(const h8*)(sWhi + lwN + k);
            h8 WRl = *(const h8*)(a.Whh_lo + ghR + k);
            h8 WZl = *(const h8*)(a.Whh_lo + ghZ + k);
            h8 WNl = *(const h8*)(a.Whh_lo + ghN + k);
            // main (hi*hi)
            MFMA16(aR, Axh, BRh);  MFMA16(aR, Ahh, WRh);
            MFMA16(aZ, Axh, BZh);  MFMA16(aZ, Ahh, WZh);
            MFMA16(aNI, Axh, BNh); MFMA16(aNH, Ahh, WNh);
            // correction (hi*lo' + lo'*hi), accumulated at 2^11 scale
            MFMA16(cR, Axh, BRl);  MFMA16(cR, Axl, BRh);
            MFMA16(cR, Ahh, WRl);  MFMA16(cR, Ahl, WRh);
            MFMA16(cZ, Axh, BZl);  MFMA16(cZ, Axl, BZh);
            MFMA16(cZ, Ahh, WZl);  MFMA16(cZ, Ahl, WZh);
            MFMA16(cNI, Axh, BNl); MFMA16(cNI, Axl, BNh);
            MFMA16(cNH, Ahh, WNl); MFMA16(cNH, Ahl, WNh);
        }

        #pragma unroll
        for (int r = 0; r < 4; ++r) {
            int row = mw * 16 + l4 * 4 + r;
            int col = nw * 16 + l15;
            sC[0 * 64 * CP + row * CP + col] = aR[r]  + cR[r]  * INV2048;
            sC[1 * 64 * CP + row * CP + col] = aZ[r]  + cZ[r]  * INV2048;
            sC[2 * 64 * CP + row * CP + col] = aNI[r] + cNI[r] * INV2048;
            sC[3 * 64 * CP + row * CP + col] = aNH[r] + cNH[r] * INV2048;
        }
        __syncthreads();

        // Gates in fp32; c-half commits straight to the NEXT state slot (no race: readers use cur)
        for (int i = tid; i < 2048; i += 512) {
            int row = i >> 5, c = i & 31;
            int j = gn * 32 + c;
            float gr  = sC[row * CP + c]               + a.b_ih[j]        + a.b_hh[j];
            float gz  = sC[64 * CP + row * CP + c]     + a.b_ih[512 + j]  + a.b_hh[512 + j];
            float gni = sC[2 * 64 * CP + row * CP + c] + a.b_ih[1024 + j];
            float gnh = sC[3 * 64 * CP + row * CP + c] + a.b_hh[1024 + j];
            float r_ = 1.f / (1.f + expf(-gr));
            float z_ = 1.f / (1.f + expf(-gz));
            float n_ = tanhf(gni + r_ * gnh);
            int grow = row0 + row;
            size_t off = (size_t)grow * DDIM + j;
            float hprev = a.hn_f32[cur * HS + off];
            float v = (1.f - z_) * n_ + z_ * hprev;
            a.bufB[off] = v;
            if (gn >= 8) {   // c-half: final value, commit to next slot
                a.hn_f32[nxt * HS + off] = v;
                fsplitS(v, &a.hn_hi[nxt * HS + off], &a.hn_lo[nxt * HS + off]);
            }
        }
        __threadfence();
        grid.sync();

        // ---------------- Phase B ----------------
        if (t < LSEQ - 1 && blk < 64) {
            // ODE MLP + h-half commit + y[t+1]  (16 batch rows per block)
            const int prow0 = blk * 16;
            _Float16* sHBhi = (_Float16*)sC;            // 16 x WST
            _Float16* sHBlo = sHBhi + 16 * WST;
            _Float16* sZ1hi = sZ1;
            _Float16* sZ1lo = sZ1 + 16 * 136;
            for (int i = tid; i < 16 * 512; i += 512) {
                int r = i >> 9, c = i & 511;
                float v = a.bufB[(size_t)(prow0 + r) * DDIM + c];
                fsplitS(v, &sHBhi[r * WST + c], &sHBlo[r * WST + c]);
            }
            __syncthreads();
            // z1 = tanh(h @ W1 + b1): 16x128, K=256; wave w -> n-tile w
            {
                floatx4 z = {0.f,0.f,0.f,0.f}, zc = {0.f,0.f,0.f,0.f};
                for (int kk = 0; kk < 8; ++kk) {
                    int k = kk * 32 + l4 * 8;
                    h8 ah = *(const h8*)(sHBhi + l15 * WST + k);
                    h8 al = *(const h8*)(sHBlo + l15 * WST + k);
                    h8 bh = *(const h8*)(a.W1T_hi + (size_t)(w * 16 + l15) * 256 + k);
                    h8 bl = *(const h8*)(a.W1T_lo + (size_t)(w * 16 + l15) * 256 + k);
                    MFMA16(z, ah, bh); MFMA16(zc, ah, bl); MFMA16(zc, al, bh);
                }
                #pragma unroll
                for (int r = 0; r < 4; ++r) {
                    int row = l4 * 4 + r;
                    int col = w * 16 + l15;
                    float zv = tanhf(z[r] + zc[r] * INV2048 + a.b1[col]);
                    fsplitS(zv, &sZ1hi[row * 136 + col], &sZ1lo[row * 136 + col]);
                }
            }
            __syncthreads();
            // f = z1 @ W2 + b2; h += dt*f; commit h-half to next slot
            {
                floatx4 f0 = {0.f,0.f,0.f,0.f}, f0c = {0.f,0.f,0.f,0.f};
                floatx4 f1 = {0.f,0.f,0.f,0.f}, f1c = {0.f,0.f,0.f,0.f};
                for (int kk = 0; kk < 4; ++kk) {
                    int k = kk * 32 + l4 * 8;
                    h8 ah = *(const h8*)(sZ1hi + l15 * 136 + k);
                    h8 al = *(const h8*)(sZ1lo + l15 * 136 + k);
                    h8 b0h = *(const h8*)(a.W2T_hi + (size_t)((2 * w) * 16 + l15) * 128 + k);
                    h8 b0l = *(const h8*)(a.W2T_lo + (size_t)((2 * w) * 16 + l15) * 128 + k);
                    h8 b1h = *(const h8*)(a.W2T_hi + (size_t)((2 * w + 1) * 16 + l15) * 128 + k);
                    h8 b1l = *(const h8*)(a.W2T_lo + (size_t)((2 * w + 1) * 16 + l15) * 128 + k);
                    MFMA16(f0, ah, b0h); MFMA16(f0c, ah, b0l); MFMA16(f0c, al, b0h);
                    MFMA16(f1, ah, b1h); MFMA16(f1c, ah, b1l); MFMA16(f1c, al, b1h);
                }
                float dts[4];
                #pragma unroll
                for (int r = 0; r < 4; ++r)
                    dts[r] = a.ext[((size_t)t * BATCH + prow0 + l4 * 4 + r) * 33 + 32];
                #pragma unroll
                for (int i2 = 0; i2 < 2; ++i2) {
                    int col = (2 * w + i2) * 16 + l15;
                    floatx4 fv  = i2 ? f1 : f0;
                    floatx4 fvc = i2 ? f1c : f0c;
                    #pragma unroll
                    for (int r = 0; r < 4; ++r) {
                        int row = l4 * 4 + r;
                        size_t off = (size_t)(prow0 + row) * DDIM + col;
                        float hnew = a.bufB[off] + dts[r] * (fv[r] + fvc[r] * INV2048 + a.b2[col]);
                        a.hn_f32[nxt * HS + off] = hnew;
                        _Float16 hi, lo;
                        fsplitS(hnew, &hi, &lo);
                        a.hn_hi[nxt * HS + off] = hi;
                        a.hn_lo[nxt * HS + off] = lo;
                        sHBhi[row * WST + col] = hi;
                        sHBlo[row * WST + col] = lo;
                    }
                }
            }
            __syncthreads();
            // y[t+1] = hn_out @ WLy + bLy (16x16, K=512), wave 0
            if (w == 0) {
                floatx4 y = {0.f,0.f,0.f,0.f}, yc = {0.f,0.f,0.f,0.f};
                for (int kk = 0; kk < 16; ++kk) {
                    int k = kk * 32 + l4 * 8;
                    h8 ah = *(const h8*)(sHBhi + l15 * WST + k);
                    h8 al = *(const h8*)(sHBlo + l15 * WST + k);
                    h8 bh = *(const h8*)(a.WLyT_hi + (size_t)l15 * 512 + k);
                    h8 bl = *(const h8*)(a.WLyT_lo + (size_t)l15 * 512 + k);
                    MFMA16(y, ah, bh); MFMA16(yc, ah, bl); MFMA16(yc, al, bh);
                }
                #pragma unroll
                for (int r = 0; r < 4; ++r)
                    a.out[((size_t)(t + 1) * BATCH + prow0 + l4 * 4 + r) * 16 + l15] =
                        y[r] + yc[r] * INV2048 + a.bLy[l15];
            }
        } else if (t < LSEQ - 1 && blk >= 64 && blk < 192) {
            // Embed step t+1 into the next xcat slot (overlapped with ODE blocks)
            embed_rows(a.ext, a.obs, a.Wu, a.bu, a.Wx, a.bx, t + 1, (blk - 64) * 8, tid,
                       (float*)sZ1, a.xcb_hi + (size_t)nxt * HS, a.xcb_lo + (size_t)nxt * HS);
        }
        __threadfence();
        grid.sync();
    }
}

extern "C" void kernel_launch(void* const* d_in, const int* in_sizes, int n_in,
                              void* d_out, int out_size, void* d_ws, size_t ws_size,
                              hipStream_t stream)
{
    (void)in_sizes; (void)n_in; (void)out_size; (void)ws_size;
    const float* ext = (const float*)d_in[0];
    const float* obs = (const float*)d_in[1];
    const float* Wu  = (const float*)d_in[2];
    const float* bu  = (const float*)d_in[3];
    const float* Wx  = (const float*)d_in[4];
    const float* bx  = (const float*)d_in[5];
    const float* Wih = (const float*)d_in[6];
    const float* Whh = (const float*)d_in[7];
    const float* bih = (const float*)d_in[8];
    const float* bhh = (const float*)d_in[9];
    const float* W1  = (const float*)d_in[10];
    const float* b1  = (const float*)d_in[11];
    const float* W2  = (const float*)d_in[12];
    const float* b2  = (const float*)d_in[13];
    const float* WLy = (const float*)d_in[14];
    const float* bLy = (const float*)d_in[15];
    float* out = (float*)d_out;

    char* ws = (char*)d_ws;
    size_t off = 0;
    auto alloc = [&](size_t bytes) -> char* {
        char* p = ws + off;
        off += (bytes + 255) & ~(size_t)255;
        return p;
    };
    // total ~20 MB (R2's ~280 MB likely overflowed ws -> device fault)
    _Float16* xcb_hi = (_Float16*)alloc(2 * HS * 2);
    _Float16* xcb_lo = (_Float16*)alloc(2 * HS * 2);
    _Float16* Wih_hi = (_Float16*)alloc((size_t)G3 * DDIM * 2);
    _Float16* Wih_lo = (_Float16*)alloc((size_t)G3 * DDIM * 2);
    _Float16* Whh_lo = (_Float16*)alloc((size_t)G3 * DDIM * 2);
    _Float16* W1T_hi = (_Float16*)alloc(128 * 256 * 2);
    _Float16* W1T_lo = (_Float16*)alloc(128 * 256 * 2);
    _Float16* W2T_hi = (_Float16*)alloc(256 * 128 * 2);
    _Float16* W2T_lo = (_Float16*)alloc(256 * 128 * 2);
    _Float16* WLyT_hi = (_Float16*)alloc(16 * 512 * 2);
    _Float16* WLyT_lo = (_Float16*)alloc(16 * 512 * 2);
    float*    hn_f32 = (float*)alloc(2 * HS * 4);
    _Float16* hn_hi  = (_Float16*)alloc(2 * HS * 2);
    _Float16* hn_lo  = (_Float16*)alloc(2 * HS * 2);
    float*    bufB   = (float*)alloc(HS * 4);

    prep_kernel<<<256, 256, 0, stream>>>(Wih, Whh, W1, W2, WLy, bLy,
                                         Wih_hi, Wih_lo, Whh_lo,
                                         W1T_hi, W1T_lo, W2T_hi, W2T_lo, WLyT_hi, WLyT_lo,
                                         hn_f32, hn_hi, hn_lo, out);
    embed0_kernel<<<128, 512, 0, stream>>>(ext, obs, Wu, bu, Wx, bx, xcb_hi, xcb_lo);

    MainArgs args;
    args.ext = ext; args.obs = obs;
    args.Wu = Wu; args.bu = bu; args.Wx = Wx; args.bx = bx;
    args.Whh = Whh; args.b_ih = bih; args.b_hh = bhh;
    args.b1 = b1; args.b2 = b2; args.bLy = bLy;
    args.Wih_hi = Wih_hi; args.Wih_lo = Wih_lo; args.Whh_lo = Whh_lo;
    args.W1T_hi = W1T_hi; args.W1T_lo = W1T_lo;
    args.W2T_hi = W2T_hi; args.W2T_lo = W2T_lo;
    args.WLyT_hi = WLyT_hi; args.WLyT_lo = WLyT_lo;
    args.xcb_hi = xcb_hi; args.xcb_lo = xcb_lo;
    args.hn_f32 = hn_f32; args.hn_hi = hn_hi; args.hn_lo = hn_lo;
    args.bufB = bufB; args.out = out;
    void* kargs[] = { &args };
    hipLaunchCooperativeKernel((const void*)main_kernel, dim3(256), dim3(512), kargs, 0, stream);
}

// Round 4
// 25386.786 us; speedup vs baseline: 1.0638x; 1.0638x over previous
//
#include <hip/hip_runtime.h>
#include <hip/hip_cooperative_groups.h>

#define LSEQ 128
#define BATCH 1024
#define DDIM 512
#define G3 1536
#define HS ((size_t)BATCH * DDIM)   // one state slot
#define INV2048 4.8828125e-4f
#define WST 520    // LDS weight row stride (halves): 1040B -> 2-way bank alias only (free)

typedef _Float16 h8 __attribute__((ext_vector_type(8)));
typedef float floatx4 __attribute__((ext_vector_type(4)));

#define MFMA16(acc, A, B) acc = __builtin_amdgcn_mfma_f32_16x16x32_f16(A, B, acc, 0, 0, 0)

// split x = hi + lo*2^-11 ; lo stored pre-scaled by 2^11 (stays in fp16 normal range)
__device__ __forceinline__ void fsplitS(float x, _Float16* hi, _Float16* lo) {
    _Float16 h = (_Float16)x;
    *hi = h;
    *lo = (_Float16)((x - (float)h) * 2048.0f);
}

// ---------------- prep: weight splits/transposes, state zero ----------------
__global__ void prep_kernel(const float* __restrict__ Wih,
                            const float* __restrict__ W1, const float* __restrict__ W2,
                            const float* __restrict__ WLy,
                            _Float16* __restrict__ Wih_lo,
                            _Float16* __restrict__ W1T_hi, _Float16* __restrict__ W1T_lo,
                            _Float16* __restrict__ W2T_hi, _Float16* __restrict__ W2T_lo,
                            _Float16* __restrict__ WLyT_hi, _Float16* __restrict__ WLyT_lo,
                            float* __restrict__ hn_f32, _Float16* __restrict__ hn_hi,
                            _Float16* __restrict__ hn_lo)
{
    int tid = blockIdx.x * 256 + threadIdx.x;   // 65536 threads
    for (int i = tid; i < G3 * DDIM; i += 65536) { _Float16 h; fsplitS(Wih[i], &h, &Wih_lo[i]); }
    for (int i = tid; i < 128 * 256; i += 65536) { int n = i >> 8, k = i & 255; fsplitS(W1[k * 128 + n], &W1T_hi[i], &W1T_lo[i]); }
    for (int i = tid; i < 256 * 128; i += 65536) { int n = i >> 7, k = i & 127; fsplitS(W2[k * 256 + n], &W2T_hi[i], &W2T_lo[i]); }
    for (int i = tid; i < 16 * 512;  i += 65536) { int n = i >> 9, k = i & 511; fsplitS(WLy[k * 16 + n], &WLyT_hi[i], &WLyT_lo[i]); }
    // zero state slot 0 only (slot 1 fully written at step 0 before first read)
    for (int i = tid; i < BATCH * DDIM; i += 65536) { hn_f32[i] = 0.f; hn_hi[i] = (_Float16)0.f; hn_lo[i] = (_Float16)0.f; }
}

// ---------------- shared embedding routine: 8 rows x 512 cols of xcat[t] ----------------
__device__ __forceinline__ void embed_rows(const float* __restrict__ ext, const float* __restrict__ obs,
                                           const float* __restrict__ Wu, const float* __restrict__ bu,
                                           const float* __restrict__ Wx, const float* __restrict__ bx,
                                           int t, int r0, int tid, float* stg,
                                           _Float16* __restrict__ oh, _Float16* __restrict__ ol)
{
    for (int i = tid; i < 256; i += 512) stg[i] = ext[((size_t)t * BATCH + r0 + (i >> 5)) * 33 + (i & 31)];
    for (int i = tid; i < 128; i += 512) stg[256 + i] = obs[((size_t)t * BATCH + r0 + (i >> 4)) * 16 + (i & 15)];
    __syncthreads();
    int c = tid;   // 512 threads <-> 512 cols
    if (c < 256) {
        float wv[32];
        #pragma unroll
        for (int k = 0; k < 32; ++k) wv[k] = Wu[k * 256 + c];
        float b = bu[c];
        for (int r = 0; r < 8; ++r) {
            float acc = b;
            #pragma unroll
            for (int k = 0; k < 32; ++k) acc += stg[r * 32 + k] * wv[k];
            size_t p = (size_t)(r0 + r) * DDIM + c;
            fsplitS(tanhf(acc), &oh[p], &ol[p]);
        }
    } else {
        int cc = c - 256;
        float wv[16];
        #pragma unroll
        for (int k = 0; k < 16; ++k) wv[k] = Wx[k * 256 + cc];
        float b = bx[cc];
        for (int r = 0; r < 8; ++r) {
            float acc = b;
            #pragma unroll
            for (int k = 0; k < 16; ++k) acc += stg[256 + r * 16 + k] * wv[k];
            size_t p = (size_t)(r0 + r) * DDIM + c;
            fsplitS(tanhf(acc), &oh[p], &ol[p]);
        }
    }
}

// ---------------- embed0: xcat for t=0 into slot 0 ----------------
__global__ void embed0_kernel(const float* __restrict__ ext, const float* __restrict__ obs,
                              const float* __restrict__ Wu, const float* __restrict__ bu,
                              const float* __restrict__ Wx, const float* __restrict__ bx,
                              _Float16* __restrict__ xcb_hi, _Float16* __restrict__ xcb_lo)
{
    __shared__ float stg[384];
    embed_rows(ext, obs, Wu, bu, Wx, bx, 0, blockIdx.x * 8, threadIdx.x, stg, xcb_hi, xcb_lo);
}

// ---------------- main persistent cooperative scan kernel ----------------
struct MainArgs {
    const float* ext;
    const float* obs;
    const float* Wu; const float* bu;
    const float* Wx; const float* bx;
    const float* Wih;       // fp32, hi-split into LDS
    const float* Whh;       // fp32, hi/lo-split into LDS
    const float* b_ih;
    const float* b_hh;
    const float* b1;
    const float* b2;
    const float* bLy;
    const _Float16* Wih_lo;                    // streamed (48 KB/block/step)
    const _Float16* W1T_hi; const _Float16* W1T_lo;
    const _Float16* W2T_hi; const _Float16* W2T_lo;
    const _Float16* WLyT_hi; const _Float16* WLyT_lo;
    _Float16* xcb_hi; _Float16* xcb_lo;        // 2 slots
    float* hn_f32;                             // 2 slots
    _Float16* hn_hi; _Float16* hn_lo;          // 2 slots
    float* bufB;
    float* out;
};

__global__ void __launch_bounds__(512, 1) main_kernel(MainArgs a)
{
    // 158,464 B total static LDS
    __shared__ _Float16 sWhhHi[48 * WST];    // 49,920 B
    __shared__ _Float16 sWhhLo[48 * WST];    // 49,920 B
    __shared__ _Float16 sWihHi[48 * WST];    // 49,920 B
    __shared__ _Float16 sZ1[2 * 16 * 136];   //  8,704 B (ODE z1 scratch / embed stage)

    namespace cg = cooperative_groups;
    cg::grid_group grid = cg::this_grid();

    const int blk  = blockIdx.x;      // 0..255
    const int gb   = blk >> 5;        // batch row-group (128 rows)
    const int gn   = blk & 31;        // hn-col group (16 cols -> 48 gate rows)
    const int tid  = threadIdx.x;
    const int lane = tid & 63;
    const int w    = tid >> 6;        // 0..7 : m-tile (16 rows)
    const int l15  = lane & 15;
    const int l4   = lane >> 4;
    const int row0 = gb * 128;
    const int arow = row0 + w * 16 + l15;   // A-fragment row
    const int j0   = gn * 16;

    // ---- fill LDS weight slices (resident across all 128 steps) ----
    for (int i = tid; i < 48 * 512; i += 512) {
        int p = i >> 9, k = i & 511;
        int grow = (p >> 4) * 512 + j0 + (p & 15);   // gate g = p>>4, col c = p&15
        float wv = a.Whh[(size_t)grow * DDIM + k];
        _Float16 hi = (_Float16)wv;
        sWhhHi[p * WST + k] = hi;
        sWhhLo[p * WST + k] = (_Float16)((wv - (float)hi) * 2048.0f);
        sWihHi[p * WST + k] = (_Float16)a.Wih[(size_t)grow * DDIM + k];
    }
    __syncthreads();

    // ---- loop-invariant per-lane constants ----
    const int jc = j0 + l15;                       // this lane's gate column
    const float bR  = a.b_ih[jc]        + a.b_hh[jc];
    const float bZ  = a.b_ih[512 + jc]  + a.b_hh[512 + jc];
    const float bNI = a.b_ih[1024 + jc];
    const float bNH = a.b_hh[1024 + jc];
    const float bly = a.bLy[l15];
    const float b1c  = a.b1[w * 16 + l15];
    const float b2c0 = a.b2[(2 * w) * 16 + l15];
    const float b2c1 = a.b2[(2 * w + 1) * 16 + l15];
    const _Float16* pWLoR = a.Wih_lo + (size_t)(jc) * DDIM;
    const _Float16* pWLoZ = a.Wih_lo + (size_t)(512 + jc) * DDIM;
    const _Float16* pWLoN = a.Wih_lo + (size_t)(1024 + jc) * DDIM;
    const _Float16* pLyH  = a.WLyT_hi + (size_t)l15 * DDIM;
    const _Float16* pLyL  = a.WLyT_lo + (size_t)l15 * DDIM;
    const _Float16* sWiR = sWihHi + l15 * WST;
    const _Float16* sWiZ = sWihHi + (16 + l15) * WST;
    const _Float16* sWiN = sWihHi + (32 + l15) * WST;
    const _Float16* sWhRh = sWhhHi + l15 * WST;
    const _Float16* sWhZh = sWhhHi + (16 + l15) * WST;
    const _Float16* sWhNh = sWhhHi + (32 + l15) * WST;
    const _Float16* sWhRl = sWhhLo + l15 * WST;
    const _Float16* sWhZl = sWhhLo + (16 + l15) * WST;
    const _Float16* sWhNl = sWhhLo + (32 + l15) * WST;

    for (int t = 0; t < LSEQ; ++t) {
        const int cur = t & 1, nxt = cur ^ 1;

        // ================= Phase A: gates GEMM (registers only) + y =================
        floatx4 aR={0.f,0.f,0.f,0.f}, aZ={0.f,0.f,0.f,0.f}, aNI={0.f,0.f,0.f,0.f}, aNH={0.f,0.f,0.f,0.f};
        floatx4 cR={0.f,0.f,0.f,0.f}, cZ={0.f,0.f,0.f,0.f}, cNI={0.f,0.f,0.f,0.f}, cNH={0.f,0.f,0.f,0.f};
        floatx4 y={0.f,0.f,0.f,0.f}, yc={0.f,0.f,0.f,0.f};

        const _Float16* xh = a.xcb_hi + (size_t)cur * HS + (size_t)arow * DDIM;
        const _Float16* xl = a.xcb_lo + (size_t)cur * HS + (size_t)arow * DDIM;
        const _Float16* hh = a.hn_hi  + (size_t)cur * HS + (size_t)arow * DDIM;
        const _Float16* hl = a.hn_lo  + (size_t)cur * HS + (size_t)arow * DDIM;

        // x-part (K=512): B-hi from LDS, B-lo streamed from L2
        for (int kk = 0; kk < 16; ++kk) {
            const int k = kk * 32 + l4 * 8;
            h8 Axh = *(const h8*)(xh + k);
            h8 Axl = *(const h8*)(xl + k);
            h8 BRh = *(const h8*)(sWiR + k);
            h8 BZh = *(const h8*)(sWiZ + k);
            h8 BNh = *(const h8*)(sWiN + k);
            h8 BRl = *(const h8*)(pWLoR + k);
            h8 BZl = *(const h8*)(pWLoZ + k);
            h8 BNl = *(const h8*)(pWLoN + k);
            MFMA16(aR, Axh, BRh);  MFMA16(aZ, Axh, BZh);  MFMA16(aNI, Axh, BNh);
            MFMA16(cR, Axh, BRl);  MFMA16(cR, Axl, BRh);
            MFMA16(cZ, Axh, BZl);  MFMA16(cZ, Axl, BZh);
            MFMA16(cNI, Axh, BNl); MFMA16(cNI, Axl, BNh);
        }
        // h-part (K=512): B hi+lo from LDS; y folded in (gn==0 blocks)
        if (gn == 0) {
            for (int kk = 0; kk < 16; ++kk) {
                const int k = kk * 32 + l4 * 8;
                h8 Ahh = *(const h8*)(hh + k);
                h8 Ahl = *(const h8*)(hl + k);
                h8 WRh = *(const h8*)(sWhRh + k);
                h8 WZh = *(const h8*)(sWhZh + k);
                h8 WNh = *(const h8*)(sWhNh + k);
                h8 WRl = *(const h8*)(sWhRl + k);
                h8 WZl = *(const h8*)(sWhZl + k);
                h8 WNl = *(const h8*)(sWhNl + k);
                MFMA16(aR, Ahh, WRh);  MFMA16(aZ, Ahh, WZh);  MFMA16(aNH, Ahh, WNh);
                MFMA16(cR, Ahh, WRl);  MFMA16(cR, Ahl, WRh);
                MFMA16(cZ, Ahh, WZl);  MFMA16(cZ, Ahl, WZh);
                MFMA16(cNH, Ahh, WNl); MFMA16(cNH, Ahl, WNh);
                h8 Lyh = *(const h8*)(pLyH + k);
                h8 Lyl = *(const h8*)(pLyL + k);
                MFMA16(y, Ahh, Lyh); MFMA16(yc, Ahh, Lyl); MFMA16(yc, Ahl, Lyh);
            }
        } else {
            for (int kk = 0; kk < 16; ++kk) {
                const int k = kk * 32 + l4 * 8;
                h8 Ahh = *(const h8*)(hh + k);
                h8 Ahl = *(const h8*)(hl + k);
                h8 WRh = *(const h8*)(sWhRh + k);
                h8 WZh = *(const h8*)(sWhZh + k);
                h8 WNh = *(const h8*)(sWhNh + k);
                h8 WRl = *(const h8*)(sWhRl + k);
                h8 WZl = *(const h8*)(sWhZl + k);
                h8 WNl = *(const h8*)(sWhNl + k);
                MFMA16(aR, Ahh, WRh);  MFMA16(aZ, Ahh, WZh);  MFMA16(aNH, Ahh, WNh);
                MFMA16(cR, Ahh, WRl);  MFMA16(cR, Ahl, WRh);
                MFMA16(cZ, Ahh, WZl);  MFMA16(cZ, Ahl, WZh);
                MFMA16(cNH, Ahh, WNl); MFMA16(cNH, Ahl, WNh);
            }
        }

        // Gates in registers (C layout: row = l4*4+r, col = l15)
        #pragma unroll
        for (int r = 0; r < 4; ++r) {
            int grow = row0 + w * 16 + l4 * 4 + r;
            size_t off = (size_t)grow * DDIM + jc;
            float gr  = aR[r]  + cR[r]  * INV2048 + bR;
            float gz  = aZ[r]  + cZ[r]  * INV2048 + bZ;
            float gni = aNI[r] + cNI[r] * INV2048 + bNI;
            float gnh = aNH[r] + cNH[r] * INV2048 + bNH;
            float r_ = 1.f / (1.f + expf(-gr));
            float z_ = 1.f / (1.f + expf(-gz));
            float n_ = tanhf(gni + r_ * gnh);
            float v = (1.f - z_) * n_ + z_ * a.hn_f32[cur * HS + off];
            a.bufB[off] = v;
            if (gn >= 16) {   // c-half: final -> commit to next slot now
                a.hn_f32[nxt * HS + off] = v;
                fsplitS(v, &a.hn_hi[nxt * HS + off], &a.hn_lo[nxt * HS + off]);
            }
        }
        if (gn == 0) {
            #pragma unroll
            for (int r = 0; r < 4; ++r) {
                int grow = row0 + w * 16 + l4 * 4 + r;
                a.out[((size_t)t * BATCH + grow) * 16 + l15] = y[r] + yc[r] * INV2048 + bly;
            }
        }

        if (t == LSEQ - 1) break;    // y[127] done; no further state needed
        __threadfence();
        grid.sync();

        // ================= Phase B: ODE MLP (blocks 0-63) | embed t+1 (64-191) =================
        if (blk < 64) {
            const int prow0 = blk * 16;
            _Float16* sZ1hi = sZ1;
            _Float16* sZ1lo = sZ1 + 16 * 136;
            // z1 = tanh(h @ W1 + b1): 16x128, K=256; A direct from bufB (fp32->split)
            {
                floatx4 z = {0.f,0.f,0.f,0.f}, zc = {0.f,0.f,0.f,0.f};
                for (int kk = 0; kk < 8; ++kk) {
                    int k = kk * 32 + l4 * 8;
                    const float* pb = a.bufB + (size_t)(prow0 + l15) * DDIM + k;
                    floatx4 w0 = *(const floatx4*)pb;
                    floatx4 w1 = *(const floatx4*)(pb + 4);
                    h8 ah, al;
                    #pragma unroll
                    for (int e = 0; e < 4; ++e) {
                        _Float16 h1 = (_Float16)w0[e]; ah[e] = h1; al[e] = (_Float16)((w0[e] - (float)h1) * 2048.f);
                        _Float16 h2 = (_Float16)w1[e]; ah[4 + e] = h2; al[4 + e] = (_Float16)((w1[e] - (float)h2) * 2048.f);
                    }
                    h8 bh = *(const h8*)(a.W1T_hi + (size_t)(w * 16 + l15) * 256 + k);
                    h8 bl = *(const h8*)(a.W1T_lo + (size_t)(w * 16 + l15) * 256 + k);
                    MFMA16(z, ah, bh); MFMA16(zc, ah, bl); MFMA16(zc, al, bh);
                }
                #pragma unroll
                for (int r = 0; r < 4; ++r) {
                    int row = l4 * 4 + r, col = w * 16 + l15;
                    float zv = tanhf(z[r] + zc[r] * INV2048 + b1c);
                    fsplitS(zv, &sZ1hi[row * 136 + col], &sZ1lo[row * 136 + col]);
                }
            }
            __syncthreads();
            // f = z1 @ W2 + b2; h += dt*f; commit h-half to next slot
            {
                floatx4 f0 = {0.f,0.f,0.f,0.f}, f0c = {0.f,0.f,0.f,0.f};
                floatx4 f1 = {0.f,0.f,0.f,0.f}, f1c = {0.f,0.f,0.f,0.f};
                for (int kk = 0; kk < 4; ++kk) {
                    int k = kk * 32 + l4 * 8;
                    h8 ah = *(const h8*)(sZ1hi + l15 * 136 + k);
                    h8 al = *(const h8*)(sZ1lo + l15 * 136 + k);
                    h8 b0h = *(const h8*)(a.W2T_hi + (size_t)((2 * w) * 16 + l15) * 128 + k);
                    h8 b0l = *(const h8*)(a.W2T_lo + (size_t)((2 * w) * 16 + l15) * 128 + k);
                    h8 b1h = *(const h8*)(a.W2T_hi + (size_t)((2 * w + 1) * 16 + l15) * 128 + k);
                    h8 b1l = *(const h8*)(a.W2T_lo + (size_t)((2 * w + 1) * 16 + l15) * 128 + k);
                    MFMA16(f0, ah, b0h); MFMA16(f0c, ah, b0l); MFMA16(f0c, al, b0h);
                    MFMA16(f1, ah, b1h); MFMA16(f1c, ah, b1l); MFMA16(f1c, al, b1h);
                }
                float dts[4];
                #pragma unroll
                for (int r = 0; r < 4; ++r)
                    dts[r] = a.ext[((size_t)t * BATCH + prow0 + l4 * 4 + r) * 33 + 32];
                #pragma unroll
                for (int i2 = 0; i2 < 2; ++i2) {
                    int col = (2 * w + i2) * 16 + l15;
                    floatx4 fv  = i2 ? f1 : f0;
                    floatx4 fvc = i2 ? f1c : f0c;
                    float b2v = i2 ? b2c1 : b2c0;
                    #pragma unroll
                    for (int r = 0; r < 4; ++r) {
                        size_t off = (size_t)(prow0 + l4 * 4 + r) * DDIM + col;
                        float hnew = a.bufB[off] + dts[r] * (fv[r] + fvc[r] * INV2048 + b2v);
                        a.hn_f32[nxt * HS + off] = hnew;
                        fsplitS(hnew, &a.hn_hi[nxt * HS + off], &a.hn_lo[nxt * HS + off]);
                    }
                }
            }
        } else if (blk < 192) {
            // embed step t+1 into next xcat slot (overlapped with ODE blocks)
            embed_rows(a.ext, a.obs, a.Wu, a.bu, a.Wx, a.bx, t + 1, (blk - 64) * 8, tid,
                       (float*)sZ1, a.xcb_hi + (size_t)nxt * HS, a.xcb_lo + (size_t)nxt * HS);
        }
        __threadfence();
        grid.sync();
    }
}

extern "C" void kernel_launch(void* const* d_in, const int* in_sizes, int n_in,
                              void* d_out, int out_size, void* d_ws, size_t ws_size,
                              hipStream_t stream)
{
    (void)in_sizes; (void)n_in; (void)out_size; (void)ws_size;
    const float* ext = (const float*)d_in[0];
    const float* obs = (const float*)d_in[1];
    const float* Wu  = (const float*)d_in[2];
    const float* bu  = (const float*)d_in[3];
    const float* Wx  = (const float*)d_in[4];
    const float* bx  = (const float*)d_in[5];
    const float* Wih = (const float*)d_in[6];
    const float* Whh = (const float*)d_in[7];
    const float* bih = (const float*)d_in[8];
    const float* bhh = (const float*)d_in[9];
    const float* W1  = (const float*)d_in[10];
    const float* b1  = (const float*)d_in[11];
    const float* W2  = (const float*)d_in[12];
    const float* b2  = (const float*)d_in[13];
    const float* WLy = (const float*)d_in[14];
    const float* bLy = (const float*)d_in[15];
    float* out = (float*)d_out;

    char* ws = (char*)d_ws;
    size_t off = 0;
    auto alloc = [&](size_t bytes) -> char* {
        char* p = ws + off;
        off += (bytes + 255) & ~(size_t)255;
        return p;
    };
    // total ~19 MB
    _Float16* xcb_hi = (_Float16*)alloc(2 * HS * 2);
    _Float16* xcb_lo = (_Float16*)alloc(2 * HS * 2);
    _Float16* Wih_lo = (_Float16*)alloc((size_t)G3 * DDIM * 2);
    _Float16* W1T_hi = (_Float16*)alloc(128 * 256 * 2);
    _Float16* W1T_lo = (_Float16*)alloc(128 * 256 * 2);
    _Float16* W2T_hi = (_Float16*)alloc(256 * 128 * 2);
    _Float16* W2T_lo = (_Float16*)alloc(256 * 128 * 2);
    _Float16* WLyT_hi = (_Float16*)alloc(16 * 512 * 2);
    _Float16* WLyT_lo = (_Float16*)alloc(16 * 512 * 2);
    float*    hn_f32 = (float*)alloc(2 * HS * 4);
    _Float16* hn_hi  = (_Float16*)alloc(2 * HS * 2);
    _Float16* hn_lo  = (_Float16*)alloc(2 * HS * 2);
    float*    bufB   = (float*)alloc(HS * 4);

    prep_kernel<<<256, 256, 0, stream>>>(Wih, W1, W2, WLy,
                                         Wih_lo, W1T_hi, W1T_lo, W2T_hi, W2T_lo,
                                         WLyT_hi, WLyT_lo, hn_f32, hn_hi, hn_lo);
    embed0_kernel<<<128, 512, 0, stream>>>(ext, obs, Wu, bu, Wx, bx, xcb_hi, xcb_lo);

    MainArgs args;
    args.ext = ext; args.obs = obs;
    args.Wu = Wu; args.bu = bu; args.Wx = Wx; args.bx = bx;
    args.Wih = Wih; args.Whh = Whh; args.b_ih = bih; args.b_hh = bhh;
    args.b1 = b1; args.b2 = b2; args.bLy = bLy;
    args.Wih_lo = Wih_lo;
    args.W1T_hi = W1T_hi; args.W1T_lo = W1T_lo;
    args.W2T_hi = W2T_hi; args.W2T_lo = W2T_lo;
    args.WLyT_hi = WLyT_hi; args.WLyT_lo = WLyT_lo;
    args.xcb_hi = xcb_hi; args.xcb_lo = xcb_lo;
    args.hn_f32 = hn_f32; args.hn_hi = hn_hi; args.hn_lo = hn_lo;
    args.bufB = bufB; args.out = out;
    void* kargs[] = { &args };
    hipLaunchCooperativeKernel((const void*)main_kernel, dim3(256), dim3(512), kargs, 0, stream);
}

// Round 5
// 9703.015 us; speedup vs baseline: 2.7832x; 2.6164x over previous
//
#include <hip/hip_runtime.h>

#define LSEQ 128
#define BATCH 1024
#define DDIM 512
#define G3 1536
#define HS ((size_t)BATCH * DDIM)   // one state slot
#define INV2048 4.8828125e-4f
#define WST 520    // LDS weight row stride (halves): 1040B -> 2-way bank alias only (free)

typedef _Float16 h8 __attribute__((ext_vector_type(8)));
typedef float floatx4 __attribute__((ext_vector_type(4)));

#define MFMA16(acc, A, B) acc = __builtin_amdgcn_mfma_f32_16x16x32_f16(A, B, acc, 0, 0, 0)

// split x = hi + lo*2^-11 ; lo stored pre-scaled by 2^11 (stays in fp16 normal range)
__device__ __forceinline__ void fsplitS(float x, _Float16* hi, _Float16* lo) {
    _Float16 h = (_Float16)x;
    *hi = h;
    *lo = (_Float16)((x - (float)h) * 2048.0f);
}

// ---------------- custom tree grid barrier (replaces cg::grid.sync) ----------------
// 64 leaves (4 WGs each) -> 8 mids (8 leaves each) -> root -> generation word.
// Max same-line contention = 8 (vs 256 for cg), counters monotonic (no reset race).
#define BAR_LEAF(i) ((i) * 32)
#define BAR_MID(i)  ((64 + (i)) * 32)
#define BAR_ROOT    (72 * 32)
#define BAR_GEN     (73 * 32)
#define BAR_WORDS   4096

__device__ __forceinline__ void grid_bar(unsigned* bar, int blk, unsigned epoch) {
    __syncthreads();
    if (threadIdx.x == 0) {
        __builtin_amdgcn_fence(__ATOMIC_RELEASE, "agent");
        const int leaf = blk >> 2;
        unsigned v = __hip_atomic_fetch_add(bar + BAR_LEAF(leaf), 1u, __ATOMIC_ACQ_REL, __HIP_MEMORY_SCOPE_AGENT);
        if (v + 1u == epoch * 4u) {
            const int mid = leaf >> 3;
            unsigned m = __hip_atomic_fetch_add(bar + BAR_MID(mid), 1u, __ATOMIC_ACQ_REL, __HIP_MEMORY_SCOPE_AGENT);
            if (m + 1u == epoch * 8u) {
                unsigned r = __hip_atomic_fetch_add(bar + BAR_ROOT, 1u, __ATOMIC_ACQ_REL, __HIP_MEMORY_SCOPE_AGENT);
                if (r + 1u == epoch * 8u) {
                    __hip_atomic_store(bar + BAR_GEN, epoch, __ATOMIC_RELEASE, __HIP_MEMORY_SCOPE_AGENT);
                }
            }
        }
        while (__hip_atomic_load(bar + BAR_GEN, __ATOMIC_RELAXED, __HIP_MEMORY_SCOPE_AGENT) < epoch)
            __builtin_amdgcn_s_sleep(2);
        __builtin_amdgcn_fence(__ATOMIC_ACQUIRE, "agent");
    }
    __syncthreads();
}

// ---------------- prep: weight splits/transposes, state zero, barrier zero ----------------
__global__ void prep_kernel(const float* __restrict__ Wih,
                            const float* __restrict__ W1, const float* __restrict__ W2,
                            const float* __restrict__ WLy,
                            _Float16* __restrict__ Wih_lo,
                            _Float16* __restrict__ W1T_hi, _Float16* __restrict__ W1T_lo,
                            _Float16* __restrict__ W2T_hi, _Float16* __restrict__ W2T_lo,
                            _Float16* __restrict__ WLyT_hi, _Float16* __restrict__ WLyT_lo,
                            float* __restrict__ hn_f32, _Float16* __restrict__ hn_hi,
                            _Float16* __restrict__ hn_lo, unsigned* __restrict__ bar)
{
    int tid = blockIdx.x * 256 + threadIdx.x;   // 65536 threads
    for (int i = tid; i < G3 * DDIM; i += 65536) { _Float16 h; fsplitS(Wih[i], &h, &Wih_lo[i]); }
    for (int i = tid; i < 128 * 256; i += 65536) { int n = i >> 8, k = i & 255; fsplitS(W1[k * 128 + n], &W1T_hi[i], &W1T_lo[i]); }
    for (int i = tid; i < 256 * 128; i += 65536) { int n = i >> 7, k = i & 127; fsplitS(W2[k * 256 + n], &W2T_hi[i], &W2T_lo[i]); }
    for (int i = tid; i < 16 * 512;  i += 65536) { int n = i >> 9, k = i & 511; fsplitS(WLy[k * 16 + n], &WLyT_hi[i], &WLyT_lo[i]); }
    // zero state slot 0 only (slot 1 fully written at step 0 before first read)
    for (int i = tid; i < BATCH * DDIM; i += 65536) { hn_f32[i] = 0.f; hn_hi[i] = (_Float16)0.f; hn_lo[i] = (_Float16)0.f; }
    for (int i = tid; i < BAR_WORDS; i += 65536) bar[i] = 0u;
}

// ---------------- shared embedding routine: 8 rows x 512 cols of xcat[t] ----------------
__device__ __forceinline__ void embed_rows(const float* __restrict__ ext, const float* __restrict__ obs,
                                           const float* __restrict__ Wu, const float* __restrict__ bu,
                                           const float* __restrict__ Wx, const float* __restrict__ bx,
                                           int t, int r0, int tid, float* stg,
                                           _Float16* __restrict__ oh, _Float16* __restrict__ ol)
{
    for (int i = tid; i < 256; i += 512) stg[i] = ext[((size_t)t * BATCH + r0 + (i >> 5)) * 33 + (i & 31)];
    for (int i = tid; i < 128; i += 512) stg[256 + i] = obs[((size_t)t * BATCH + r0 + (i >> 4)) * 16 + (i & 15)];
    __syncthreads();
    int c = tid;   // 512 threads <-> 512 cols
    if (c < 256) {
        float wv[32];
        #pragma unroll
        for (int k = 0; k < 32; ++k) wv[k] = Wu[k * 256 + c];
        float b = bu[c];
        for (int r = 0; r < 8; ++r) {
            float acc = b;
            #pragma unroll
            for (int k = 0; k < 32; ++k) acc += stg[r * 32 + k] * wv[k];
            size_t p = (size_t)(r0 + r) * DDIM + c;
            fsplitS(tanhf(acc), &oh[p], &ol[p]);
        }
    } else {
        int cc = c - 256;
        float wv[16];
        #pragma unroll
        for (int k = 0; k < 16; ++k) wv[k] = Wx[k * 256 + cc];
        float b = bx[cc];
        for (int r = 0; r < 8; ++r) {
            float acc = b;
            #pragma unroll
            for (int k = 0; k < 16; ++k) acc += stg[256 + r * 16 + k] * wv[k];
            size_t p = (size_t)(r0 + r) * DDIM + c;
            fsplitS(tanhf(acc), &oh[p], &ol[p]);
        }
    }
}

// ---------------- embed0: xcat for t=0 into slot 0 ----------------
__global__ void embed0_kernel(const float* __restrict__ ext, const float* __restrict__ obs,
                              const float* __restrict__ Wu, const float* __restrict__ bu,
                              const float* __restrict__ Wx, const float* __restrict__ bx,
                              _Float16* __restrict__ xcb_hi, _Float16* __restrict__ xcb_lo)
{
    __shared__ float stg[384];
    embed_rows(ext, obs, Wu, bu, Wx, bx, 0, blockIdx.x * 8, threadIdx.x, stg, xcb_hi, xcb_lo);
}

// ---------------- main persistent cooperative scan kernel ----------------
struct MainArgs {
    const float* ext;
    const float* obs;
    const float* Wu; const float* bu;
    const float* Wx; const float* bx;
    const float* Wih;       // fp32, hi-split into LDS
    const float* Whh;       // fp32, hi/lo-split into LDS
    const float* b_ih;
    const float* b_hh;
    const float* b1;
    const float* b2;
    const float* bLy;
    const _Float16* Wih_lo;                    // streamed (48 KB/block/step)
    const _Float16* W1T_hi; const _Float16* W1T_lo;
    const _Float16* W2T_hi; const _Float16* W2T_lo;
    const _Float16* WLyT_hi; const _Float16* WLyT_lo;
    _Float16* xcb_hi; _Float16* xcb_lo;        // 2 slots
    float* hn_f32;                             // 2 slots
    _Float16* hn_hi; _Float16* hn_lo;          // 2 slots
    float* bufB;
    float* out;
    unsigned* bar;
};

__global__ void __launch_bounds__(512, 1) main_kernel(MainArgs a)
{
    // 158,464 B total static LDS
    __shared__ _Float16 sWhhHi[48 * WST];    // 49,920 B
    __shared__ _Float16 sWhhLo[48 * WST];    // 49,920 B
    __shared__ _Float16 sWihHi[48 * WST];    // 49,920 B
    __shared__ _Float16 sZ1[2 * 16 * 136];   //  8,704 B (ODE z1 scratch / embed stage)

    const int blk  = blockIdx.x;      // 0..255
    const int gb   = blk >> 5;        // batch row-group (128 rows)
    const int gn   = blk & 31;        // hn-col group (16 cols -> 48 gate rows)
    const int tid  = threadIdx.x;
    const int lane = tid & 63;
    const int w    = tid >> 6;        // 0..7 : m-tile (16 rows)
    const int l15  = lane & 15;
    const int l4   = lane >> 4;
    const int row0 = gb * 128;
    const int arow = row0 + w * 16 + l15;   // A-fragment row
    const int j0   = gn * 16;

    // ---- fill LDS weight slices (resident across all 128 steps) ----
    for (int i = tid; i < 48 * 512; i += 512) {
        int p = i >> 9, k = i & 511;
        int grow = (p >> 4) * 512 + j0 + (p & 15);   // gate g = p>>4, col c = p&15
        float wv = a.Whh[(size_t)grow * DDIM + k];
        _Float16 hi = (_Float16)wv;
        sWhhHi[p * WST + k] = hi;
        sWhhLo[p * WST + k] = (_Float16)((wv - (float)hi) * 2048.0f);
        sWihHi[p * WST + k] = (_Float16)a.Wih[(size_t)grow * DDIM + k];
    }
    __syncthreads();

    // ---- loop-invariant per-lane constants ----
    const int jc = j0 + l15;                       // this lane's gate column
    const float bR  = a.b_ih[jc]        + a.b_hh[jc];
    const float bZ  = a.b_ih[512 + jc]  + a.b_hh[512 + jc];
    const float bNI = a.b_ih[1024 + jc];
    const float bNH = a.b_hh[1024 + jc];
    const float bly = a.bLy[l15];
    const float b1c  = a.b1[w * 16 + l15];
    const float b2c0 = a.b2[(2 * w) * 16 + l15];
    const float b2c1 = a.b2[(2 * w + 1) * 16 + l15];
    const _Float16* pWLoR = a.Wih_lo + (size_t)(jc) * DDIM;
    const _Float16* pWLoZ = a.Wih_lo + (size_t)(512 + jc) * DDIM;
    const _Float16* pWLoN = a.Wih_lo + (size_t)(1024 + jc) * DDIM;
    const _Float16* pLyH  = a.WLyT_hi + (size_t)l15 * DDIM;
    const _Float16* pLyL  = a.WLyT_lo + (size_t)l15 * DDIM;
    const _Float16* sWiR = sWihHi + l15 * WST;
    const _Float16* sWiZ = sWihHi + (16 + l15) * WST;
    const _Float16* sWiN = sWihHi + (32 + l15) * WST;
    const _Float16* sWhRh = sWhhHi + l15 * WST;
    const _Float16* sWhZh = sWhhHi + (16 + l15) * WST;
    const _Float16* sWhNh = sWhhHi + (32 + l15) * WST;
    const _Float16* sWhRl = sWhhLo + l15 * WST;
    const _Float16* sWhZl = sWhhLo + (16 + l15) * WST;
    const _Float16* sWhNl = sWhhLo + (32 + l15) * WST;

    unsigned epoch = 0;

    for (int t = 0; t < LSEQ; ++t) {
        const int cur = t & 1, nxt = cur ^ 1;

        // ================= Phase A: gates GEMM (registers only) + y =================
        floatx4 aR={0.f,0.f,0.f,0.f}, aZ={0.f,0.f,0.f,0.f}, aNI={0.f,0.f,0.f,0.f}, aNH={0.f,0.f,0.f,0.f};
        floatx4 cR={0.f,0.f,0.f,0.f}, cZ={0.f,0.f,0.f,0.f}, cNI={0.f,0.f,0.f,0.f}, cNH={0.f,0.f,0.f,0.f};
        floatx4 y={0.f,0.f,0.f,0.f}, yc={0.f,0.f,0.f,0.f};

        const _Float16* xh = a.xcb_hi + (size_t)cur * HS + (size_t)arow * DDIM;
        const _Float16* xl = a.xcb_lo + (size_t)cur * HS + (size_t)arow * DDIM;
        const _Float16* hh = a.hn_hi  + (size_t)cur * HS + (size_t)arow * DDIM;
        const _Float16* hl = a.hn_lo  + (size_t)cur * HS + (size_t)arow * DDIM;

        // x-part (K=512): B-hi from LDS, B-lo streamed from L2
        for (int kk = 0; kk < 16; ++kk) {
            const int k = kk * 32 + l4 * 8;
            h8 Axh = *(const h8*)(xh + k);
            h8 Axl = *(const h8*)(xl + k);
            h8 BRh = *(const h8*)(sWiR + k);
            h8 BZh = *(const h8*)(sWiZ + k);
            h8 BNh = *(const h8*)(sWiN + k);
            h8 BRl = *(const h8*)(pWLoR + k);
            h8 BZl = *(const h8*)(pWLoZ + k);
            h8 BNl = *(const h8*)(pWLoN + k);
            MFMA16(aR, Axh, BRh);  MFMA16(aZ, Axh, BZh);  MFMA16(aNI, Axh, BNh);
            MFMA16(cR, Axh, BRl);  MFMA16(cR, Axl, BRh);
            MFMA16(cZ, Axh, BZl);  MFMA16(cZ, Axl, BZh);
            MFMA16(cNI, Axh, BNl); MFMA16(cNI, Axl, BNh);
        }
        // h-part (K=512): B hi+lo from LDS; y folded in (gn==0 blocks)
        if (gn == 0) {
            for (int kk = 0; kk < 16; ++kk) {
                const int k = kk * 32 + l4 * 8;
                h8 Ahh = *(const h8*)(hh + k);
                h8 Ahl = *(const h8*)(hl + k);
                h8 WRh = *(const h8*)(sWhRh + k);
                h8 WZh = *(const h8*)(sWhZh + k);
                h8 WNh = *(const h8*)(sWhNh + k);
                h8 WRl = *(const h8*)(sWhRl + k);
                h8 WZl = *(const h8*)(sWhZl + k);
                h8 WNl = *(const h8*)(sWhNl + k);
                MFMA16(aR, Ahh, WRh);  MFMA16(aZ, Ahh, WZh);  MFMA16(aNH, Ahh, WNh);
                MFMA16(cR, Ahh, WRl);  MFMA16(cR, Ahl, WRh);
                MFMA16(cZ, Ahh, WZl);  MFMA16(cZ, Ahl, WZh);
                MFMA16(cNH, Ahh, WNl); MFMA16(cNH, Ahl, WNh);
                h8 Lyh = *(const h8*)(pLyH + k);
                h8 Lyl = *(const h8*)(pLyL + k);
                MFMA16(y, Ahh, Lyh); MFMA16(yc, Ahh, Lyl); MFMA16(yc, Ahl, Lyh);
            }
        } else {
            for (int kk = 0; kk < 16; ++kk) {
                const int k = kk * 32 + l4 * 8;
                h8 Ahh = *(const h8*)(hh + k);
                h8 Ahl = *(const h8*)(hl + k);
                h8 WRh = *(const h8*)(sWhRh + k);
                h8 WZh = *(const h8*)(sWhZh + k);
                h8 WNh = *(const h8*)(sWhNh + k);
                h8 WRl = *(const h8*)(sWhRl + k);
                h8 WZl = *(const h8*)(sWhZl + k);
                h8 WNl = *(const h8*)(sWhNl + k);
                MFMA16(aR, Ahh, WRh);  MFMA16(aZ, Ahh, WZh);  MFMA16(aNH, Ahh, WNh);
                MFMA16(cR, Ahh, WRl);  MFMA16(cR, Ahl, WRh);
                MFMA16(cZ, Ahh, WZl);  MFMA16(cZ, Ahl, WZh);
                MFMA16(cNH, Ahh, WNl); MFMA16(cNH, Ahl, WNh);
            }
        }

        // Gates in registers (C layout: row = l4*4+r, col = l15)
        #pragma unroll
        for (int r = 0; r < 4; ++r) {
            int grow = row0 + w * 16 + l4 * 4 + r;
            size_t off = (size_t)grow * DDIM + jc;
            float gr  = aR[r]  + cR[r]  * INV2048 + bR;
            float gz  = aZ[r]  + cZ[r]  * INV2048 + bZ;
            float gni = aNI[r] + cNI[r] * INV2048 + bNI;
            float gnh = aNH[r] + cNH[r] * INV2048 + bNH;
            float r_ = 1.f / (1.f + expf(-gr));
            float z_ = 1.f / (1.f + expf(-gz));
            float n_ = tanhf(gni + r_ * gnh);
            float v = (1.f - z_) * n_ + z_ * a.hn_f32[cur * HS + off];
            a.bufB[off] = v;
            if (gn >= 16) {   // c-half: final -> commit to next slot now
                a.hn_f32[nxt * HS + off] = v;
                fsplitS(v, &a.hn_hi[nxt * HS + off], &a.hn_lo[nxt * HS + off]);
            }
        }
        if (gn == 0) {
            #pragma unroll
            for (int r = 0; r < 4; ++r) {
                int grow = row0 + w * 16 + l4 * 4 + r;
                a.out[((size_t)t * BATCH + grow) * 16 + l15] = y[r] + yc[r] * INV2048 + bly;
            }
        }

        if (t == LSEQ - 1) break;    // y[127] done; no further state needed
        grid_bar(a.bar, blk, ++epoch);

        // ================= Phase B: ODE MLP (blocks 0-63) | embed t+1 (64-191) =================
        if (blk < 64) {
            const int prow0 = blk * 16;
            _Float16* sZ1hi = sZ1;
            _Float16* sZ1lo = sZ1 + 16 * 136;
            // z1 = tanh(h @ W1 + b1): 16x128, K=256; A direct from bufB (fp32->split)
            {
                floatx4 z = {0.f,0.f,0.f,0.f}, zc = {0.f,0.f,0.f,0.f};
                for (int kk = 0; kk < 8; ++kk) {
                    int k = kk * 32 + l4 * 8;
                    const float* pb = a.bufB + (size_t)(prow0 + l15) * DDIM + k;
                    floatx4 w0 = *(const floatx4*)pb;
                    floatx4 w1 = *(const floatx4*)(pb + 4);
                    h8 ah, al;
                    #pragma unroll
                    for (int e = 0; e < 4; ++e) {
                        _Float16 h1 = (_Float16)w0[e]; ah[e] = h1; al[e] = (_Float16)((w0[e] - (float)h1) * 2048.f);
                        _Float16 h2 = (_Float16)w1[e]; ah[4 + e] = h2; al[4 + e] = (_Float16)((w1[e] - (float)h2) * 2048.f);
                    }
                    h8 bh = *(const h8*)(a.W1T_hi + (size_t)(w * 16 + l15) * 256 + k);
                    h8 bl = *(const h8*)(a.W1T_lo + (size_t)(w * 16 + l15) * 256 + k);
                    MFMA16(z, ah, bh); MFMA16(zc, ah, bl); MFMA16(zc, al, bh);
                }
                #pragma unroll
                for (int r = 0; r < 4; ++r) {
                    int row = l4 * 4 + r, col = w * 16 + l15;
                    float zv = tanhf(z[r] + zc[r] * INV2048 + b1c);
                    fsplitS(zv, &sZ1hi[row * 136 + col], &sZ1lo[row * 136 + col]);
                }
            }
            __syncthreads();
            // f = z1 @ W2 + b2; h += dt*f; commit h-half to next slot
            {
                floatx4 f0 = {0.f,0.f,0.f,0.f}, f0c = {0.f,0.f,0.f,0.f};
                floatx4 f1 = {0.f,0.f,0.f,0.f}, f1c = {0.f,0.f,0.f,0.f};
                for (int kk = 0; kk < 4; ++kk) {
                    int k = kk * 32 + l4 * 8;
                    h8 ah = *(const h8*)(sZ1hi + l15 * 136 + k);
                    h8 al = *(const h8*)(sZ1lo + l15 * 136 + k);
                    h8 b0h = *(const h8*)(a.W2T_hi + (size_t)((2 * w) * 16 + l15) * 128 + k);
                    h8 b0l = *(const h8*)(a.W2T_lo + (size_t)((2 * w) * 16 + l15) * 128 + k);
                    h8 b1h = *(const h8*)(a.W2T_hi + (size_t)((2 * w + 1) * 16 + l15) * 128 + k);
                    h8 b1l = *(const h8*)(a.W2T_lo + (size_t)((2 * w + 1) * 16 + l15) * 128 + k);
                    MFMA16(f0, ah, b0h); MFMA16(f0c, ah, b0l); MFMA16(f0c, al, b0h);
                    MFMA16(f1, ah, b1h); MFMA16(f1c, ah, b1l); MFMA16(f1c, al, b1h);
                }
                float dts[4];
                #pragma unroll
                for (int r = 0; r < 4; ++r)
                    dts[r] = a.ext[((size_t)t * BATCH + prow0 + l4 * 4 + r) * 33 + 32];
                #pragma unroll
                for (int i2 = 0; i2 < 2; ++i2) {
                    int col = (2 * w + i2) * 16 + l15;
                    floatx4 fv  = i2 ? f1 : f0;
                    floatx4 fvc = i2 ? f1c : f0c;
                    float b2v = i2 ? b2c1 : b2c0;
                    #pragma unroll
                    for (int r = 0; r < 4; ++r) {
                        size_t off = (size_t)(prow0 + l4 * 4 + r) * DDIM + col;
                        float hnew = a.bufB[off] + dts[r] * (fv[r] + fvc[r] * INV2048 + b2v);
                        a.hn_f32[nxt * HS + off] = hnew;
                        fsplitS(hnew, &a.hn_hi[nxt * HS + off], &a.hn_lo[nxt * HS + off]);
                    }
                }
            }
        } else if (blk < 192) {
            // embed step t+1 into next xcat slot (overlapped with ODE blocks)
            embed_rows(a.ext, a.obs, a.Wu, a.bu, a.Wx, a.bx, t + 1, (blk - 64) * 8, tid,
                       (float*)sZ1, a.xcb_hi + (size_t)nxt * HS, a.xcb_lo + (size_t)nxt * HS);
        }
        grid_bar(a.bar, blk, ++epoch);
    }
}

extern "C" void kernel_launch(void* const* d_in, const int* in_sizes, int n_in,
                              void* d_out, int out_size, void* d_ws, size_t ws_size,
                              hipStream_t stream)
{
    (void)in_sizes; (void)n_in; (void)out_size; (void)ws_size;
    const float* ext = (const float*)d_in[0];
    const float* obs = (const float*)d_in[1];
    const float* Wu  = (const float*)d_in[2];
    const float* bu  = (const float*)d_in[3];
    const float* Wx  = (const float*)d_in[4];
    const float* bx  = (const float*)d_in[5];
    const float* Wih = (const float*)d_in[6];
    const float* Whh = (const float*)d_in[7];
    const float* bih = (const float*)d_in[8];
    const float* bhh = (const float*)d_in[9];
    const float* W1  = (const float*)d_in[10];
    const float* b1  = (const float*)d_in[11];
    const float* W2  = (const float*)d_in[12];
    const float* b2  = (const float*)d_in[13];
    const float* WLy = (const float*)d_in[14];
    const float* bLy = (const float*)d_in[15];
    float* out = (float*)d_out;

    char* ws = (char*)d_ws;
    size_t off = 0;
    auto alloc = [&](size_t bytes) -> char* {
        char* p = ws + off;
        off += (bytes + 255) & ~(size_t)255;
        return p;
    };
    // total ~19 MB
    _Float16* xcb_hi = (_Float16*)alloc(2 * HS * 2);
    _Float16* xcb_lo = (_Float16*)alloc(2 * HS * 2);
    _Float16* Wih_lo = (_Float16*)alloc((size_t)G3 * DDIM * 2);
    _Float16* W1T_hi = (_Float16*)alloc(128 * 256 * 2);
    _Float16* W1T_lo = (_Float16*)alloc(128 * 256 * 2);
    _Float16* W2T_hi = (_Float16*)alloc(256 * 128 * 2);
    _Float16* W2T_lo = (_Float16*)alloc(256 * 128 * 2);
    _Float16* WLyT_hi = (_Float16*)alloc(16 * 512 * 2);
    _Float16* WLyT_lo = (_Float16*)alloc(16 * 512 * 2);
    float*    hn_f32 = (float*)alloc(2 * HS * 4);
    _Float16* hn_hi  = (_Float16*)alloc(2 * HS * 2);
    _Float16* hn_lo  = (_Float16*)alloc(2 * HS * 2);
    float*    bufB   = (float*)alloc(HS * 4);
    unsigned* bar    = (unsigned*)alloc(BAR_WORDS * 4);

    prep_kernel<<<256, 256, 0, stream>>>(Wih, W1, W2, WLy,
                                         Wih_lo, W1T_hi, W1T_lo, W2T_hi, W2T_lo,
                                         WLyT_hi, WLyT_lo, hn_f32, hn_hi, hn_lo, bar);
    embed0_kernel<<<128, 512, 0, stream>>>(ext, obs, Wu, bu, Wx, bx, xcb_hi, xcb_lo);

    MainArgs args;
    args.ext = ext; args.obs = obs;
    args.Wu = Wu; args.bu = bu; args.Wx = Wx; args.bx = bx;
    args.Wih = Wih; args.Whh = Whh; args.b_ih = bih; args.b_hh = bhh;
    args.b1 = b1; args.b2 = b2; args.bLy = bLy;
    args.Wih_lo = Wih_lo;
    args.W1T_hi = W1T_hi; args.W1T_lo = W1T_lo;
    args.W2T_hi = W2T_hi; args.W2T_lo = W2T_lo;
    args.WLyT_hi = WLyT_hi; args.WLyT_lo = WLyT_lo;
    args.xcb_hi = xcb_hi; args.xcb_lo = xcb_lo;
    args.hn_f32 = hn_f32; args.hn_hi = hn_hi; args.hn_lo = hn_lo;
    args.bufB = bufB; args.out = out;
    args.bar = bar;
    void* kargs[] = { &args };
    hipLaunchCooperativeKernel((const void*)main_kernel, dim3(256), dim3(512), kargs, 0, stream);
}

// Round 6
// 8977.071 us; speedup vs baseline: 3.0083x; 1.0809x over previous
//
#include <hip/hip_runtime.h>

#define LSEQ 128
#define BATCH 1024
#define DDIM 512
#define G3 1536
#define HS ((size_t)BATCH * DDIM)   // one state slot
#define INV2048 4.8828125e-4f
#define WST 520    // LDS weight row stride (halves)

typedef _Float16 h8 __attribute__((ext_vector_type(8)));
typedef float floatx4 __attribute__((ext_vector_type(4)));

#define MFMA16(acc, A, B) acc = __builtin_amdgcn_mfma_f32_16x16x32_f16(A, B, acc, 0, 0, 0)

// split x = hi + lo*2^-11 ; lo stored pre-scaled by 2^11 (stays in fp16 normal range)
__device__ __forceinline__ void fsplitS(float x, _Float16* hi, _Float16* lo) {
    _Float16 h = (_Float16)x;
    *hi = h;
    *lo = (_Float16)((x - (float)h) * 2048.0f);
}

// ---------------- barrier / registration memory map (words) ----------------
// [0 .. 73*32]      : startup tree barrier (all 256 blocks, used twice)
// [4096 + g*256]    : group g: 4 leaf lines (i*32), root (+128), gen (+160)
// [7168 + x*32]     : per-XCD registration counters
// [7936]            : mode flag (1 = XCD-pure groups)
#define BAR_LEAF(i) ((i) * 32)
#define BAR_MID(i)  ((64 + (i)) * 32)
#define BAR_ROOT    (72 * 32)
#define BAR_GEN     (73 * 32)
#define BAR_WORDS   8192
#define GB_BASE(g)  (4096 + (g) * 256)
#define XCD_CNT(x)  (7168 + (x) * 32)
#define MODE_FLAG   7936
#define HWREG_XCC_ID_IMM (20 | (31 << 11))   // hwreg(HW_REG_XCC_ID, 0, 32)

// full-grid tree barrier (startup only)
__device__ __forceinline__ void grid_bar(unsigned* bar, int blk, unsigned epoch) {
    __syncthreads();
    if (threadIdx.x == 0) {
        __builtin_amdgcn_fence(__ATOMIC_RELEASE, "agent");
        const int leaf = blk >> 2;
        unsigned v = __hip_atomic_fetch_add(bar + BAR_LEAF(leaf), 1u, __ATOMIC_ACQ_REL, __HIP_MEMORY_SCOPE_AGENT);
        if (v + 1u == epoch * 4u) {
            const int mid = leaf >> 3;
            unsigned m = __hip_atomic_fetch_add(bar + BAR_MID(mid), 1u, __ATOMIC_ACQ_REL, __HIP_MEMORY_SCOPE_AGENT);
            if (m + 1u == epoch * 8u) {
                unsigned r = __hip_atomic_fetch_add(bar + BAR_ROOT, 1u, __ATOMIC_ACQ_REL, __HIP_MEMORY_SCOPE_AGENT);
                if (r + 1u == epoch * 8u)
                    __hip_atomic_store(bar + BAR_GEN, epoch, __ATOMIC_RELEASE, __HIP_MEMORY_SCOPE_AGENT);
            }
        }
        while (__hip_atomic_load(bar + BAR_GEN, __ATOMIC_RELAXED, __HIP_MEMORY_SCOPE_AGENT) < epoch)
            __builtin_amdgcn_s_sleep(2);
        __builtin_amdgcn_fence(__ATOMIC_ACQUIRE, "agent");
    }
    __syncthreads();
}

// group-local barrier: 32 members, 4 leaves x 8 + root; fences agent-scope (proven R5)
__device__ __forceinline__ void group_bar(unsigned* bar, int group, int mem, unsigned epoch) {
    __syncthreads();
    if (threadIdx.x == 0) {
        __builtin_amdgcn_fence(__ATOMIC_RELEASE, "agent");
        unsigned* g = bar + GB_BASE(group);
        unsigned v = __hip_atomic_fetch_add(g + (mem >> 3) * 32, 1u, __ATOMIC_ACQ_REL, __HIP_MEMORY_SCOPE_AGENT);
        if (v + 1u == epoch * 8u) {
            unsigned r = __hip_atomic_fetch_add(g + 128, 1u, __ATOMIC_ACQ_REL, __HIP_MEMORY_SCOPE_AGENT);
            if (r + 1u == epoch * 4u)
                __hip_atomic_store(g + 160, epoch, __ATOMIC_RELEASE, __HIP_MEMORY_SCOPE_AGENT);
        }
        while (__hip_atomic_load(g + 160, __ATOMIC_RELAXED, __HIP_MEMORY_SCOPE_AGENT) < epoch)
            __builtin_amdgcn_s_sleep(2);
        __builtin_amdgcn_fence(__ATOMIC_ACQUIRE, "agent");
    }
    __syncthreads();
}

// ---------------- prep: weight splits/transposes, state zero, barrier zero ----------------
__global__ void prep_kernel(const float* __restrict__ Wih,
                            const float* __restrict__ W1, const float* __restrict__ W2,
                            const float* __restrict__ WLy,
                            _Float16* __restrict__ Wih_lo,
                            _Float16* __restrict__ W1T_hi, _Float16* __restrict__ W1T_lo,
                            _Float16* __restrict__ W2T_hi, _Float16* __restrict__ W2T_lo,
                            _Float16* __restrict__ WLyT_hi, _Float16* __restrict__ WLyT_lo,
                            float* __restrict__ hn_f32, _Float16* __restrict__ hn_hi,
                            _Float16* __restrict__ hn_lo, unsigned* __restrict__ bar)
{
    int tid = blockIdx.x * 256 + threadIdx.x;   // 65536 threads
    for (int i = tid; i < G3 * DDIM; i += 65536) { _Float16 h; fsplitS(Wih[i], &h, &Wih_lo[i]); }
    for (int i = tid; i < 128 * 256; i += 65536) { int n = i >> 8, k = i & 255; fsplitS(W1[k * 128 + n], &W1T_hi[i], &W1T_lo[i]); }
    for (int i = tid; i < 256 * 128; i += 65536) { int n = i >> 7, k = i & 127; fsplitS(W2[k * 256 + n], &W2T_hi[i], &W2T_lo[i]); }
    for (int i = tid; i < 16 * 512;  i += 65536) { int n = i >> 9, k = i & 511; fsplitS(WLy[k * 16 + n], &WLyT_hi[i], &WLyT_lo[i]); }
    for (int i = tid; i < BATCH * DDIM; i += 65536) { hn_f32[i] = 0.f; hn_hi[i] = (_Float16)0.f; hn_lo[i] = (_Float16)0.f; }
    for (int i = tid; i < BAR_WORDS; i += 65536) bar[i] = 0u;
}

// ---------------- shared embedding routine: 8 rows x 512 cols of xcat[t] ----------------
__device__ __forceinline__ void embed_rows(const float* __restrict__ ext, const float* __restrict__ obs,
                                           const float* __restrict__ Wu, const float* __restrict__ bu,
                                           const float* __restrict__ Wx, const float* __restrict__ bx,
                                           int t, int r0, int tid, float* stg,
                                           _Float16* __restrict__ oh, _Float16* __restrict__ ol)
{
    for (int i = tid; i < 256; i += 512) stg[i] = ext[((size_t)t * BATCH + r0 + (i >> 5)) * 33 + (i & 31)];
    for (int i = tid; i < 128; i += 512) stg[256 + i] = obs[((size_t)t * BATCH + r0 + (i >> 4)) * 16 + (i & 15)];
    __syncthreads();
    int c = tid;   // 512 threads <-> 512 cols
    if (c < 256) {
        float wv[32];
        #pragma unroll
        for (int k = 0; k < 32; ++k) wv[k] = Wu[k * 256 + c];
        float b = bu[c];
        for (int r = 0; r < 8; ++r) {
            float acc = b;
            #pragma unroll
            for (int k = 0; k < 32; ++k) acc += stg[r * 32 + k] * wv[k];
            size_t p = (size_t)(r0 + r) * DDIM + c;
            fsplitS(tanhf(acc), &oh[p], &ol[p]);
        }
    } else {
        int cc = c - 256;
        float wv[16];
        #pragma unroll
        for (int k = 0; k < 16; ++k) wv[k] = Wx[k * 256 + cc];
        float b = bx[cc];
        for (int r = 0; r < 8; ++r) {
            float acc = b;
            #pragma unroll
            for (int k = 0; k < 16; ++k) acc += stg[256 + r * 16 + k] * wv[k];
            size_t p = (size_t)(r0 + r) * DDIM + c;
            fsplitS(tanhf(acc), &oh[p], &ol[p]);
        }
    }
}

// ---------------- embed0: xcat for t=0 into slot 0 ----------------
__global__ void embed0_kernel(const float* __restrict__ ext, const float* __restrict__ obs,
                              const float* __restrict__ Wu, const float* __restrict__ bu,
                              const float* __restrict__ Wx, const float* __restrict__ bx,
                              _Float16* __restrict__ xcb_hi, _Float16* __restrict__ xcb_lo)
{
    __shared__ float stg[384];
    embed_rows(ext, obs, Wu, bu, Wx, bx, 0, blockIdx.x * 8, threadIdx.x, stg, xcb_hi, xcb_lo);
}

// ---------------- main persistent cooperative scan kernel ----------------
struct MainArgs {
    const float* ext;
    const float* obs;
    const float* Wu; const float* bu;
    const float* Wx; const float* bx;
    const float* Wih;
    const float* Whh;
    const float* b_ih;
    const float* b_hh;
    const float* b1;
    const float* b2;
    const float* bLy;
    const _Float16* Wih_lo;
    const _Float16* W1T_hi; const _Float16* W1T_lo;
    const _Float16* W2T_hi; const _Float16* W2T_lo;
    const _Float16* WLyT_hi; const _Float16* WLyT_lo;
    _Float16* xcb_hi; _Float16* xcb_lo;        // 2 slots
    float* hn_f32;                             // 2 slots
    _Float16* hn_hi; _Float16* hn_lo;          // 2 slots
    float* bufB;
    float* out;
    unsigned* bar;
};

__global__ void __launch_bounds__(512, 1) main_kernel(MainArgs a)
{
    // 158,464 B total static LDS
    __shared__ _Float16 sWhhHi[48 * WST];    // 49,920 B
    __shared__ _Float16 sWhhLo[48 * WST];    // 49,920 B
    __shared__ _Float16 sWihHi[48 * WST];    // 49,920 B
    __shared__ _Float16 sZ1[2 * 16 * 136];   //  8,704 B (ODE z1 scratch / embed stage)
    __shared__ int sGroup, sMem;

    const int blk  = blockIdx.x;      // 0..255
    const int tid  = threadIdx.x;
    const int lane = tid & 63;
    const int w    = tid >> 6;        // 0..7 : m-tile (16 rows)
    const int l15  = lane & 15;
    const int l4   = lane >> 4;
    unsigned* bar  = a.bar;

    // ---- XCD discovery: groups become XCD-pure when dispatch is round-robin ----
    if (tid == 0) {
        unsigned xcd = __builtin_amdgcn_s_getreg(HWREG_XCC_ID_IMM) & 0xFu;
        if (xcd > 7u) xcd = (unsigned)(blk & 7);
        unsigned slot = __hip_atomic_fetch_add(bar + XCD_CNT(xcd), 1u, __ATOMIC_ACQ_REL, __HIP_MEMORY_SCOPE_AGENT);
        sGroup = (int)xcd; sMem = (int)slot;
    }
    grid_bar(bar, blk, 1);
    if (blk == 0 && tid == 0) {
        unsigned ok = 1;
        for (int x = 0; x < 8; ++x)
            ok &= (__hip_atomic_load(bar + XCD_CNT(x), __ATOMIC_RELAXED, __HIP_MEMORY_SCOPE_AGENT) == 32u);
        __hip_atomic_store(bar + MODE_FLAG, ok, __ATOMIC_RELEASE, __HIP_MEMORY_SCOPE_AGENT);
    }
    grid_bar(bar, blk, 2);
    if (tid == 0) {
        unsigned mode = __hip_atomic_load(bar + MODE_FLAG, __ATOMIC_RELAXED, __HIP_MEMORY_SCOPE_AGENT);
        if (mode == 0u || sMem > 31) { sGroup = blk >> 5; sMem = blk & 31; }  // correct for ANY mapping
    }
    __syncthreads();
    const int group = sGroup;         // batch slice (128 rows)
    const int mem   = sMem;           // 0..31: col-group within slice
    const int gn    = mem;
    const int row0  = group * 128;
    const int arow  = row0 + w * 16 + l15;
    const int j0    = gn * 16;

    // ---- fill LDS weight slices (resident across all 128 steps) ----
    for (int i = tid; i < 48 * 512; i += 512) {
        int p = i >> 9, k = i & 511;
        int grow = (p >> 4) * 512 + j0 + (p & 15);
        float wv = a.Whh[(size_t)grow * DDIM + k];
        _Float16 hi = (_Float16)wv;
        sWhhHi[p * WST + k] = hi;
        sWhhLo[p * WST + k] = (_Float16)((wv - (float)hi) * 2048.0f);
        sWihHi[p * WST + k] = (_Float16)a.Wih[(size_t)grow * DDIM + k];
    }
    __syncthreads();

    // ---- loop-invariant per-lane constants ----
    const int jc = j0 + l15;
    const float bR  = a.b_ih[jc]        + a.b_hh[jc];
    const float bZ  = a.b_ih[512 + jc]  + a.b_hh[512 + jc];
    const float bNI = a.b_ih[1024 + jc];
    const float bNH = a.b_hh[1024 + jc];
    const float bly = a.bLy[l15];
    const float b1c  = a.b1[w * 16 + l15];
    const float b2c0 = a.b2[(2 * w) * 16 + l15];
    const float b2c1 = a.b2[(2 * w + 1) * 16 + l15];
    const _Float16* pWLoR = a.Wih_lo + (size_t)(jc) * DDIM;
    const _Float16* pWLoZ = a.Wih_lo + (size_t)(512 + jc) * DDIM;
    const _Float16* pWLoN = a.Wih_lo + (size_t)(1024 + jc) * DDIM;
    const _Float16* pLyH  = a.WLyT_hi + (size_t)l15 * DDIM;
    const _Float16* pLyL  = a.WLyT_lo + (size_t)l15 * DDIM;
    const _Float16* sWiR = sWihHi + l15 * WST;
    const _Float16* sWiZ = sWihHi + (16 + l15) * WST;
    const _Float16* sWiN = sWihHi + (32 + l15) * WST;
    const _Float16* sWhRh = sWhhHi + l15 * WST;
    const _Float16* sWhZh = sWhhHi + (16 + l15) * WST;
    const _Float16* sWhNh = sWhhHi + (32 + l15) * WST;
    const _Float16* sWhRl = sWhhLo + l15 * WST;
    const _Float16* sWhZl = sWhhLo + (16 + l15) * WST;
    const _Float16* sWhNl = sWhhLo + (32 + l15) * WST;

    unsigned epoch = 0;

    for (int t = 0; t < LSEQ; ++t) {
        const int cur = t & 1, nxt = cur ^ 1;

        // ================= Phase A: gates GEMM (registers only) + y =================
        floatx4 aR={0.f,0.f,0.f,0.f}, aZ={0.f,0.f,0.f,0.f}, aNI={0.f,0.f,0.f,0.f}, aNH={0.f,0.f,0.f,0.f};
        floatx4 cR={0.f,0.f,0.f,0.f}, cZ={0.f,0.f,0.f,0.f}, cNI={0.f,0.f,0.f,0.f}, cNH={0.f,0.f,0.f,0.f};
        floatx4 y={0.f,0.f,0.f,0.f}, yc={0.f,0.f,0.f,0.f};

        const _Float16* xh = a.xcb_hi + (size_t)cur * HS + (size_t)arow * DDIM;
        const _Float16* xl = a.xcb_lo + (size_t)cur * HS + (size_t)arow * DDIM;
        const _Float16* hh = a.hn_hi  + (size_t)cur * HS + (size_t)arow * DDIM;
        const _Float16* hl = a.hn_lo  + (size_t)cur * HS + (size_t)arow * DDIM;

        for (int kk = 0; kk < 16; ++kk) {
            const int k = kk * 32 + l4 * 8;
            h8 Axh = *(const h8*)(xh + k);
            h8 Axl = *(const h8*)(xl + k);
            h8 BRh = *(const h8*)(sWiR + k);
            h8 BZh = *(const h8*)(sWiZ + k);
            h8 BNh = *(const h8*)(sWiN + k);
            h8 BRl = *(const h8*)(pWLoR + k);
            h8 BZl = *(const h8*)(pWLoZ + k);
            h8 BNl = *(const h8*)(pWLoN + k);
            MFMA16(aR, Axh, BRh);  MFMA16(aZ, Axh, BZh);  MFMA16(aNI, Axh, BNh);
            MFMA16(cR, Axh, BRl);  MFMA16(cR, Axl, BRh);
            MFMA16(cZ, Axh, BZl);  MFMA16(cZ, Axl, BZh);
            MFMA16(cNI, Axh, BNl); MFMA16(cNI, Axl, BNh);
        }
        if (gn == 0) {
            for (int kk = 0; kk < 16; ++kk) {
                const int k = kk * 32 + l4 * 8;
                h8 Ahh = *(const h8*)(hh + k);
                h8 Ahl = *(const h8*)(hl + k);
                h8 WRh = *(const h8*)(sWhRh + k);
                h8 WZh = *(const h8*)(sWhZh + k);
                h8 WNh = *(const h8*)(sWhNh + k);
                h8 WRl = *(const h8*)(sWhRl + k);
                h8 WZl = *(const h8*)(sWhZl + k);
                h8 WNl = *(const h8*)(sWhNl + k);
                MFMA16(aR, Ahh, WRh);  MFMA16(aZ, Ahh, WZh);  MFMA16(aNH, Ahh, WNh);
                MFMA16(cR, Ahh, WRl);  MFMA16(cR, Ahl, WRh);
                MFMA16(cZ, Ahh, WZl);  MFMA16(cZ, Ahl, WZh);
                MFMA16(cNH, Ahh, WNl); MFMA16(cNH, Ahl, WNh);
                h8 Lyh = *(const h8*)(pLyH + k);
                h8 Lyl = *(const h8*)(pLyL + k);
                MFMA16(y, Ahh, Lyh); MFMA16(yc, Ahh, Lyl); MFMA16(yc, Ahl, Lyh);
            }
        } else {
            for (int kk = 0; kk < 16; ++kk) {
                const int k = kk * 32 + l4 * 8;
                h8 Ahh = *(const h8*)(hh + k);
                h8 Ahl = *(const h8*)(hl + k);
                h8 WRh = *(const h8*)(sWhRh + k);
                h8 WZh = *(const h8*)(sWhZh + k);
                h8 WNh = *(const h8*)(sWhNh + k);
                h8 WRl = *(const h8*)(sWhRl + k);
                h8 WZl = *(const h8*)(sWhZl + k);
                h8 WNl = *(const h8*)(sWhNl + k);
                MFMA16(aR, Ahh, WRh);  MFMA16(aZ, Ahh, WZh);  MFMA16(aNH, Ahh, WNh);
                MFMA16(cR, Ahh, WRl);  MFMA16(cR, Ahl, WRh);
                MFMA16(cZ, Ahh, WZl);  MFMA16(cZ, Ahl, WZh);
                MFMA16(cNH, Ahh, WNl); MFMA16(cNH, Ahl, WNh);
            }
        }

        // Gates in registers (C layout: row = l4*4+r, col = l15)
        #pragma unroll
        for (int r = 0; r < 4; ++r) {
            int grow = row0 + w * 16 + l4 * 4 + r;
            size_t off = (size_t)grow * DDIM + jc;
            float gr  = aR[r]  + cR[r]  * INV2048 + bR;
            float gz  = aZ[r]  + cZ[r]  * INV2048 + bZ;
            float gni = aNI[r] + cNI[r] * INV2048 + bNI;
            float gnh = aNH[r] + cNH[r] * INV2048 + bNH;
            float r_ = 1.f / (1.f + expf(-gr));
            float z_ = 1.f / (1.f + expf(-gz));
            float n_ = tanhf(gni + r_ * gnh);
            float v = (1.f - z_) * n_ + z_ * a.hn_f32[cur * HS + off];
            a.bufB[off] = v;
            if (gn >= 16) {   // c-half: final -> commit to next slot now
                a.hn_f32[nxt * HS + off] = v;
                fsplitS(v, &a.hn_hi[nxt * HS + off], &a.hn_lo[nxt * HS + off]);
            }
        }
        if (gn == 0) {
            #pragma unroll
            for (int r = 0; r < 4; ++r) {
                int grow = row0 + w * 16 + l4 * 4 + r;
                a.out[((size_t)t * BATCH + grow) * 16 + l15] = y[r] + yc[r] * INV2048 + bly;
            }
        }

        if (t == LSEQ - 1) break;    // y[127] done; no further state needed
        group_bar(bar, group, mem, ++epoch);

        // ===== Phase B (group-local): ODE MLP (mem 0-7) | embed t+1 (mem 8-23) =====
        if (mem < 8) {
            const int prow0 = row0 + mem * 16;
            _Float16* sZ1hi = sZ1;
            _Float16* sZ1lo = sZ1 + 16 * 136;
            // z1 = tanh(h @ W1 + b1): 16x128, K=256; A direct from bufB (fp32->split)
            {
                floatx4 z = {0.f,0.f,0.f,0.f}, zc = {0.f,0.f,0.f,0.f};
                for (int kk = 0; kk < 8; ++kk) {
                    int k = kk * 32 + l4 * 8;
                    const float* pb = a.bufB + (size_t)(prow0 + l15) * DDIM + k;
                    floatx4 w0 = *(const floatx4*)pb;
                    floatx4 w1 = *(const floatx4*)(pb + 4);
                    h8 ah, al;
                    #pragma unroll
                    for (int e = 0; e < 4; ++e) {
                        _Float16 h1 = (_Float16)w0[e]; ah[e] = h1; al[e] = (_Float16)((w0[e] - (float)h1) * 2048.f);
                        _Float16 h2 = (_Float16)w1[e]; ah[4 + e] = h2; al[4 + e] = (_Float16)((w1[e] - (float)h2) * 2048.f);
                    }
                    h8 bh = *(const h8*)(a.W1T_hi + (size_t)(w * 16 + l15) * 256 + k);
                    h8 bl = *(const h8*)(a.W1T_lo + (size_t)(w * 16 + l15) * 256 + k);
                    MFMA16(z, ah, bh); MFMA16(zc, ah, bl); MFMA16(zc, al, bh);
                }
                #pragma unroll
                for (int r = 0; r < 4; ++r) {
                    int row = l4 * 4 + r, col = w * 16 + l15;
                    float zv = tanhf(z[r] + zc[r] * INV2048 + b1c);
                    fsplitS(zv, &sZ1hi[row * 136 + col], &sZ1lo[row * 136 + col]);
                }
            }
            __syncthreads();
            // f = z1 @ W2 + b2; h += dt*f; commit h-half to next slot
            {
                floatx4 f0 = {0.f,0.f,0.f,0.f}, f0c = {0.f,0.f,0.f,0.f};
                floatx4 f1 = {0.f,0.f,0.f,0.f}, f1c = {0.f,0.f,0.f,0.f};
                for (int kk = 0; kk < 4; ++kk) {
                    int k = kk * 32 + l4 * 8;
                    h8 ah = *(const h8*)(sZ1hi + l15 * 136 + k);
                    h8 al = *(const h8*)(sZ1lo + l15 * 136 + k);
                    h8 b0h = *(const h8*)(a.W2T_hi + (size_t)((2 * w) * 16 + l15) * 128 + k);
                    h8 b0l = *(const h8*)(a.W2T_lo + (size_t)((2 * w) * 16 + l15) * 128 + k);
                    h8 b1h = *(const h8*)(a.W2T_hi + (size_t)((2 * w + 1) * 16 + l15) * 128 + k);
                    h8 b1l = *(const h8*)(a.W2T_lo + (size_t)((2 * w + 1) * 16 + l15) * 128 + k);
                    MFMA16(f0, ah, b0h); MFMA16(f0c, ah, b0l); MFMA16(f0c, al, b0h);
                    MFMA16(f1, ah, b1h); MFMA16(f1c, ah, b1l); MFMA16(f1c, al, b1h);
                }
                float dts[4];
                #pragma unroll
                for (int r = 0; r < 4; ++r)
                    dts[r] = a.ext[((size_t)t * BATCH + prow0 + l4 * 4 + r) * 33 + 32];
                #pragma unroll
                for (int i2 = 0; i2 < 2; ++i2) {
                    int col = (2 * w + i2) * 16 + l15;
                    floatx4 fv  = i2 ? f1 : f0;
                    floatx4 fvc = i2 ? f1c : f0c;
                    float b2v = i2 ? b2c1 : b2c0;
                    #pragma unroll
                    for (int r = 0; r < 4; ++r) {
                        size_t off = (size_t)(prow0 + l4 * 4 + r) * DDIM + col;
                        float hnew = a.bufB[off] + dts[r] * (fv[r] + fvc[r] * INV2048 + b2v);
                        a.hn_f32[nxt * HS + off] = hnew;
                        fsplitS(hnew, &a.hn_hi[nxt * HS + off], &a.hn_lo[nxt * HS + off]);
                    }
                }
            }
        } else if (mem < 24) {
            // embed step t+1 (group's own rows) into next xcat slot
            embed_rows(a.ext, a.obs, a.Wu, a.bu, a.Wx, a.bx, t + 1, row0 + (mem - 8) * 8, tid,
                       (float*)sZ1, a.xcb_hi + (size_t)nxt * HS, a.xcb_lo + (size_t)nxt * HS);
        }
        group_bar(bar, group, mem, ++epoch);
    }
}

extern "C" void kernel_launch(void* const* d_in, const int* in_sizes, int n_in,
                              void* d_out, int out_size, void* d_ws, size_t ws_size,
                              hipStream_t stream)
{
    (void)in_sizes; (void)n_in; (void)out_size; (void)ws_size;
    const float* ext = (const float*)d_in[0];
    const float* obs = (const float*)d_in[1];
    const float* Wu  = (const float*)d_in[2];
    const float* bu  = (const float*)d_in[3];
    const float* Wx  = (const float*)d_in[4];
    const float* bx  = (const float*)d_in[5];
    const float* Wih = (const float*)d_in[6];
    const float* Whh = (const float*)d_in[7];
    const float* bih = (const float*)d_in[8];
    const float* bhh = (const float*)d_in[9];
    const float* W1  = (const float*)d_in[10];
    const float* b1  = (const float*)d_in[11];
    const float* W2  = (const float*)d_in[12];
    const float* b2  = (const float*)d_in[13];
    const float* WLy = (const float*)d_in[14];
    const float* bLy = (const float*)d_in[15];
    float* out = (float*)d_out;

    char* ws = (char*)d_ws;
    size_t off = 0;
    auto alloc = [&](size_t bytes) -> char* {
        char* p = ws + off;
        off += (bytes + 255) & ~(size_t)255;
        return p;
    };
    // total ~19 MB
    _Float16* xcb_hi = (_Float16*)alloc(2 * HS * 2);
    _Float16* xcb_lo = (_Float16*)alloc(2 * HS * 2);
    _Float16* Wih_lo = (_Float16*)alloc((size_t)G3 * DDIM * 2);
    _Float16* W1T_hi = (_Float16*)alloc(128 * 256 * 2);
    _Float16* W1T_lo = (_Float16*)alloc(128 * 256 * 2);
    _Float16* W2T_hi = (_Float16*)alloc(256 * 128 * 2);
    _Float16* W2T_lo = (_Float16*)alloc(256 * 128 * 2);
    _Float16* WLyT_hi = (_Float16*)alloc(16 * 512 * 2);
    _Float16* WLyT_lo = (_Float16*)alloc(16 * 512 * 2);
    float*    hn_f32 = (float*)alloc(2 * HS * 4);
    _Float16* hn_hi  = (_Float16*)alloc(2 * HS * 2);
    _Float16* hn_lo  = (_Float16*)alloc(2 * HS * 2);
    float*    bufB   = (float*)alloc(HS * 4);
    unsigned* bar    = (unsigned*)alloc(BAR_WORDS * 4);

    prep_kernel<<<256, 256, 0, stream>>>(Wih, W1, W2, WLy,
                                         Wih_lo, W1T_hi, W1T_lo, W2T_hi, W2T_lo,
                                         WLyT_hi, WLyT_lo, hn_f32, hn_hi, hn_lo, bar);
    embed0_kernel<<<128, 512, 0, stream>>>(ext, obs, Wu, bu, Wx, bx, xcb_hi, xcb_lo);

    MainArgs args;
    args.ext = ext; args.obs = obs;
    args.Wu = Wu; args.bu = bu; args.Wx = Wx; args.bx = bx;
    args.Wih = Wih; args.Whh = Whh; args.b_ih = bih; args.b_hh = bhh;
    args.b1 = b1; args.b2 = b2; args.bLy = bLy;
    args.Wih_lo = Wih_lo;
    args.W1T_hi = W1T_hi; args.W1T_lo = W1T_lo;
    args.W2T_hi = W2T_hi; args.W2T_lo = W2T_lo;
    args.WLyT_hi = WLyT_hi; args.WLyT_lo = WLyT_lo;
    args.xcb_hi = xcb_hi; args.xcb_lo = xcb_lo;
    args.hn_f32 = hn_f32; args.hn_hi = hn_hi; args.hn_lo = hn_lo;
    args.bufB = bufB; args.out = out;
    args.bar = bar;
    void* kargs[] = { &args };
    hipLaunchCooperativeKernel((const void*)main_kernel, dim3(256), dim3(512), kargs, 0, stream);
}